// Round 2
// baseline (662.749 us; speedup 1.0000x reference)
//
#include <hip/hip_runtime.h>
#include <cstdio>

typedef unsigned short u16;
typedef __bf16 bf16x8 __attribute__((ext_vector_type(8)));
typedef float f32x4 __attribute__((ext_vector_type(4)));
typedef unsigned short us4 __attribute__((ext_vector_type(4)));
typedef unsigned short us8 __attribute__((ext_vector_type(8)));

__device__ __forceinline__ u16 f2bf(float f) {
    union { float f; unsigned u; } x; x.f = f;
    unsigned u = x.u + 0x7fffu + ((x.u >> 16) & 1u);   // RNE
    return (u16)(u >> 16);
}
__device__ __forceinline__ float bf2f(u16 u) {
    union { unsigned u; float f; } x; x.u = ((unsigned)u) << 16;
    return x.f;
}

// ---------------------------------------------------------------------------
// NT GEMM: C[M,N] = A[M,K] * B[N,K]^T, bf16 in, fp32 accumulate.
// 128x128 tile, BK=32, 256 threads (4 waves, 2x2), 16x16x32 bf16 MFMA.
// grid: (N/128, M/128, batch)
// ---------------------------------------------------------------------------
template<bool HAS_BIAS, bool HAS_RESID, bool OUT_BF16>
__global__ __launch_bounds__(256)
void gemm_nt(const u16* __restrict__ A, const u16* __restrict__ Bm,
             void* __restrict__ Cm, const float* __restrict__ bias,
             const float* __restrict__ resid,
             int K, int lda, int ldb, int ldc,
             long sA, long sB, long sC, float scale)
{
    __shared__ __align__(16) u16 lA[128 * 32];   // [row][k] row-major, 64B row stride
    __shared__ __align__(16) u16 lB[128 * 32];

    const int tid = threadIdx.x;
    const long bz = blockIdx.z;
    A  += bz * sA;
    Bm += bz * sB;
    const long cbase = bz * sC;
    const int m0 = blockIdx.y * 128;
    const int n0 = blockIdx.x * 128;

    const int lane = tid & 63;
    const int w  = tid >> 6;
    const int wr = w >> 1, wc = w & 1;        // wave 64x64 sub-tile
    const int fr = lane & 15;                 // A row / B col within fragment
    const int kg = lane >> 4;                 // k-group (0..3) of 8

    f32x4 acc[4][4] = {};

    const int nk = K >> 5;
    for (int kt = 0; kt < nk; ++kt) {
        // stage A,B tiles: 8KB each via global_load_lds width=16
#pragma unroll
        for (int i = 0; i < 2; ++i) {
            int c = i * 256 + tid;            // chunk 0..511
            int row = c >> 2, seg = c & 3;    // 4x16B per 64B row
            const u16* srcA = A + (long)(m0 + row) * lda + (kt * 32 + seg * 8);
            __builtin_amdgcn_global_load_lds(
                (const __attribute__((address_space(1))) void*)srcA,
                (__attribute__((address_space(3))) void*)(&lA[c * 8]), 16, 0, 0);
            const u16* srcB = Bm + (long)(n0 + row) * ldb + (kt * 32 + seg * 8);
            __builtin_amdgcn_global_load_lds(
                (const __attribute__((address_space(1))) void*)srcB,
                (__attribute__((address_space(3))) void*)(&lB[c * 8]), 16, 0, 0);
        }
        __syncthreads();   // drains vmcnt: staged data visible

        bf16x8 af[4], bfv[4];
#pragma unroll
        for (int mf = 0; mf < 4; ++mf)
            af[mf] = *(const bf16x8*)&lA[(wr * 64 + mf * 16 + fr) * 32 + kg * 8];
#pragma unroll
        for (int nf = 0; nf < 4; ++nf)
            bfv[nf] = *(const bf16x8*)&lB[(wc * 64 + nf * 16 + fr) * 32 + kg * 8];
#pragma unroll
        for (int mf = 0; mf < 4; ++mf)
#pragma unroll
            for (int nf = 0; nf < 4; ++nf)
                acc[mf][nf] = __builtin_amdgcn_mfma_f32_16x16x32_bf16(
                    af[mf], bfv[nf], acc[mf][nf], 0, 0, 0);
        __syncthreads();   // compute done before next stage overwrites
    }

    // epilogue: C/D layout col=lane&15, row=(lane>>4)*4+reg  [m89-verified]
    const int orow = m0 + wr * 64 + kg * 4;
    const int ocol = n0 + wc * 64 + fr;
#pragma unroll
    for (int mf = 0; mf < 4; ++mf) {
#pragma unroll
        for (int r = 0; r < 4; ++r) {
            const int m = orow + mf * 16 + r;
#pragma unroll
            for (int nf = 0; nf < 4; ++nf) {
                const int n = ocol + nf * 16;
                float v = acc[mf][nf][r] * scale;
                if (HAS_BIAS)  v += bias[n];
                if (HAS_RESID) v += resid[cbase + (long)m * ldc + n];
                if (OUT_BF16)  ((u16*)Cm)[cbase + (long)m * ldc + n] = f2bf(v);
                else           ((float*)Cm)[cbase + (long)m * ldc + n] = v;
            }
        }
    }
}

// ---------------------------------------------------------------------------
// LayerNorm over D=1024, one block (256 thr) per row.
// IN_BF16/OUT_BF16 select dtypes. Safe in-place (row read fully before write).
// ---------------------------------------------------------------------------
template<bool IN_BF16, bool OUT_BF16>
__global__ __launch_bounds__(256)
void ln1024(const void* in, const float* __restrict__ g,
            const float* __restrict__ beta, void* out)
{
    const long row = blockIdx.x;
    const int tid = threadIdx.x;
    float x0, x1, x2, x3;
    if (IN_BF16) {
        const us4 v = ((const us4*)in)[row * 256 + tid];
        x0 = bf2f(v[0]); x1 = bf2f(v[1]); x2 = bf2f(v[2]); x3 = bf2f(v[3]);
    } else {
        const float4 v = ((const float4*)in)[row * 256 + tid];
        x0 = v.x; x1 = v.y; x2 = v.z; x3 = v.w;
    }
    float s  = x0 + x1 + x2 + x3;
    float s2 = x0 * x0 + x1 * x1 + x2 * x2 + x3 * x3;
#pragma unroll
    for (int off = 32; off > 0; off >>= 1) {
        s  += __shfl_xor(s, off);
        s2 += __shfl_xor(s2, off);
    }
    __shared__ float rs[4], rq[4];
    if ((tid & 63) == 0) { rs[tid >> 6] = s; rq[tid >> 6] = s2; }
    __syncthreads();
    const float S  = rs[0] + rs[1] + rs[2] + rs[3];
    const float S2 = rq[0] + rq[1] + rq[2] + rq[3];
    const float mu = S * (1.0f / 1024.0f);
    const float var = S2 * (1.0f / 1024.0f) - mu * mu;
    const float rstd = rsqrtf(var + 1e-5f);
    const float4 gg = ((const float4*)g)[tid];
    const float4 bb = ((const float4*)beta)[tid];
    const float y0 = (x0 - mu) * rstd * gg.x + bb.x;
    const float y1 = (x1 - mu) * rstd * gg.y + bb.y;
    const float y2 = (x2 - mu) * rstd * gg.z + bb.z;
    const float y3 = (x3 - mu) * rstd * gg.w + bb.w;
    if (OUT_BF16) {
        us4 o; o[0] = f2bf(y0); o[1] = f2bf(y1); o[2] = f2bf(y2); o[3] = f2bf(y3);
        ((us4*)out)[row * 256 + tid] = o;
    } else {
        float4 o; o.x = y0; o.y = y1; o.z = y2; o.w = y3;
        ((float4*)out)[row * 256 + tid] = o;
    }
}

// ---------------------------------------------------------------------------
// Softmax over width 2048, bf16 in -> bf16 out, IN-PLACE. One block per row.
// ---------------------------------------------------------------------------
__global__ __launch_bounds__(256)
void softmax2048_bf16(u16* io)
{
    const long row = blockIdx.x;
    const int tid = threadIdx.x;
    const us8 v = ((const us8*)io)[row * 256 + tid];
    float x[8];
#pragma unroll
    for (int i = 0; i < 8; ++i) x[i] = bf2f(v[i]);
    float m = x[0];
#pragma unroll
    for (int i = 1; i < 8; ++i) m = fmaxf(m, x[i]);
#pragma unroll
    for (int off = 32; off > 0; off >>= 1) m = fmaxf(m, __shfl_xor(m, off));
    __shared__ float rm[4], rsum[4];
    if ((tid & 63) == 0) rm[tid >> 6] = m;
    __syncthreads();
    m = fmaxf(fmaxf(rm[0], rm[1]), fmaxf(rm[2], rm[3]));
    float e[8];
    float s = 0.f;
#pragma unroll
    for (int i = 0; i < 8; ++i) { e[i] = __expf(x[i] - m); s += e[i]; }
#pragma unroll
    for (int off = 32; off > 0; off >>= 1) s += __shfl_xor(s, off);
    if ((tid & 63) == 0) rsum[tid >> 6] = s;
    __syncthreads();
    s = rsum[0] + rsum[1] + rsum[2] + rsum[3];
    const float inv = 1.0f / s;
    us8 o;
#pragma unroll
    for (int i = 0; i < 8; ++i) o[i] = f2bf(e[i] * inv);
    ((us8*)io)[row * 256 + tid] = o;
}

// fp32 -> bf16 cast, 8 elems/thread
__global__ __launch_bounds__(256)
void cast_f32_bf16(const float* __restrict__ in, u16* __restrict__ out, long n8)
{
    const long i = (long)blockIdx.x * 256 + threadIdx.x;
    if (i >= n8) return;
    const float4 a = ((const float4*)in)[i * 2];
    const float4 b = ((const float4*)in)[i * 2 + 1];
    us8 o;
    o[0] = f2bf(a.x); o[1] = f2bf(a.y); o[2] = f2bf(a.z); o[3] = f2bf(a.w);
    o[4] = f2bf(b.x); o[5] = f2bf(b.y); o[6] = f2bf(b.z); o[7] = f2bf(b.w);
    ((us8*)out)[i] = o;
}

// transpose + cast: fp32 [R,C] -> bf16 [C,R]. block (32,8), grid (C/32, R/32)
__global__ __launch_bounds__(256)
void tcast_f32_bf16(const float* __restrict__ in, u16* __restrict__ out,
                    int R, int C)
{
    __shared__ float t[32][33];
    const int tx = threadIdx.x, ty = threadIdx.y;
    const int c0 = blockIdx.x * 32, r0 = blockIdx.y * 32;
#pragma unroll
    for (int i = 0; i < 4; ++i)
        t[ty + i * 8][tx] = in[(long)(r0 + ty + i * 8) * C + c0 + tx];
    __syncthreads();
#pragma unroll
    for (int i = 0; i < 4; ++i)
        out[(long)(c0 + ty + i * 8) * R + r0 + tx] = f2bf(t[tx][ty + i * 8]);
}

// batched bf16 transpose: [R,C] -> [C,R] per batch. grid (C/32, R/32, batch)
__global__ __launch_bounds__(256)
void t_bf16_batched(const u16* __restrict__ in, u16* __restrict__ out,
                    int R, int C)
{
    __shared__ u16 t[32][34];
    const int tx = threadIdx.x, ty = threadIdx.y;
    const int c0 = blockIdx.x * 32, r0 = blockIdx.y * 32;
    const long base = (long)blockIdx.z * R * C;
#pragma unroll
    for (int i = 0; i < 4; ++i)
        t[ty + i * 8][tx] = in[base + (long)(r0 + ty + i * 8) * C + c0 + tx];
    __syncthreads();
#pragma unroll
    for (int i = 0; i < 4; ++i)
        out[base + (long)(c0 + ty + i * 8) * R + r0 + tx] = t[tx][ty + i * 8];
}

// ---------------------------------------------------------------------------
extern "C" void kernel_launch(void* const* d_in, const int* in_sizes, int n_in,
                              void* d_out, int out_size, void* d_ws, size_t ws_size,
                              hipStream_t stream)
{
    const float* H_l      = (const float*)d_in[0];
    const float* H_a      = (const float*)d_in[1];
    const float* W_text   = (const float*)d_in[2];
    const float* b_text   = (const float*)d_in[3];
    const float* W_audio  = (const float*)d_in[4];
    const float* b_audio  = (const float*)d_in[5];
    const float* W_out    = (const float*)d_in[6];
    const float* b_out    = (const float*)d_in[7];
    const float* g1       = (const float*)d_in[8];
    const float* beta1    = (const float*)d_in[9];
    const float* g2       = (const float*)d_in[10];
    const float* beta2    = (const float*)d_in[11];
    const float* g_out    = (const float*)d_in[12];
    const float* beta_out = (const float*)d_in[13];
    (void)in_sizes; (void)n_in; (void)out_size;

    const int B = 16, L = 1024, S = 2048, DT = 1024, DA = 768, H = 1024;

    // ---------------- workspace layout (~245.5 MiB, heavy overlay) ---------
    // R0 [0, 80Mi):  Hl_bf16(32Mi) + Ha_bf16(48Mi); both dead after G2, then
    //                scores/alpha bf16 (64Mi) overlays from offset 0.
    // A  [80,112Mi): text_p bf16 -> (in-place LN) Q bf16 -> (after G3) Hh bf16
    // C  [112,176Mi): audio_p bf16 (= V)
    // D  [176,240Mi): K bf16 -> (after attn) out_pre fp32 (both exactly 64Mi)
    // W  [240,~245.5Mi): transposed bf16 weights
    // Vt lives in d_out (exactly 64Mi); final LN overwrites all of d_out.
    char* ws = (char*)d_ws;
    const size_t SZ_HLB = (size_t)B * L * DT * 2;          // 33,554,432
    const size_t SZ_HAB = (size_t)B * S * DA * 2;          // 50,331,648
    const size_t O_A    = SZ_HLB + SZ_HAB;                 // 83,886,080
    const size_t SZ_A   = (size_t)B * L * H * 2;           // 33,554,432
    const size_t O_C    = O_A + SZ_A;                      // 117,440,512
    const size_t SZ_C   = (size_t)B * S * H * 2;           // 67,108,864
    const size_t O_D    = O_C + SZ_C;                      // 184,549,376
    const size_t SZ_D   = (size_t)B * S * H * 2;           // 67,108,864 (== B*L*H*4)
    const size_t O_W    = O_D + SZ_D;                      // 251,658,240
    const size_t need   = O_W + (size_t)(DT * H + DA * H + H * H) * 2;

    if (ws_size < need) {
        fprintf(stderr, "[kernel_launch] ws_size=%zu < needed=%zu — aborting launches\n",
                ws_size, need);
        return;
    }

    u16*   Hlb     = (u16*)(ws);                 // dies after G1
    u16*   Hab     = (u16*)(ws + SZ_HLB);        // dies after G2
    u16*   Scores  = (u16*)(ws);                 // born at G3 (overlays Hlb/Hab)
    u16*   Abuf    = (u16*)(ws + O_A);           // text_p -> Q -> Hh
    u16*   Vbuf    = (u16*)(ws + O_C);           // audio_p = V
    u16*   Kbuf    = (u16*)(ws + O_D);           // K
    float* OutPre  = (float*)(ws + O_D);         // out_pre (after K dies)
    u16*   Wt_text  = (u16*)(ws + O_W);
    u16*   Wt_audio = Wt_text + (size_t)DT * H;
    u16*   Wt_out   = Wt_audio + (size_t)DA * H;
    u16*   Vt      = (u16*)d_out;                // 64 MiB, dies before final LN

    const float scale = 0.03125f; // 1/sqrt(1024)

    // input casts to bf16
    cast_f32_bf16<<<(B * L * DT / 8 + 255) / 256, 256, 0, stream>>>(H_l, Hlb, (long)B * L * DT / 8);
    cast_f32_bf16<<<(B * S * DA / 8 + 255) / 256, 256, 0, stream>>>(H_a, Hab, (long)B * S * DA / 8);
    // weight transposes [K,N] -> [N,K] bf16
    tcast_f32_bf16<<<dim3(H / 32, DT / 32), dim3(32, 8), 0, stream>>>(W_text, Wt_text, DT, H);
    tcast_f32_bf16<<<dim3(H / 32, DA / 32), dim3(32, 8), 0, stream>>>(W_audio, Wt_audio, DA, H);
    tcast_f32_bf16<<<dim3(H / 32, H / 32),  dim3(32, 8), 0, stream>>>(W_out, Wt_out, H, H);

    // G1: text_p = H_l @ W_text + b_text   [16384,1024] bf16
    gemm_nt<true, false, true><<<dim3(H / 128, B * L / 128, 1), 256, 0, stream>>>(
        Hlb, Wt_text, Abuf, b_text, nullptr, DT, DT, DT, H, 0, 0, 0, 1.0f);
    // LN1 in-place: text_p -> Q
    ln1024<true, true><<<B * L, 256, 0, stream>>>(Abuf, g1, beta1, Abuf);

    // G2: audio_p = H_a @ W_audio + b_audio [32768,1024] bf16 (= V)
    gemm_nt<true, false, true><<<dim3(H / 128, B * S / 128, 1), 256, 0, stream>>>(
        Hab, Wt_audio, Vbuf, b_audio, nullptr, DA, DA, DA, H, 0, 0, 0, 1.0f);
    // LN2: audio_p -> K
    ln1024<true, true><<<B * S, 256, 0, stream>>>(Vbuf, g2, beta2, Kbuf);

    // V [S,H] -> Vt [H,S] per batch (Vt lives in d_out)
    t_bf16_batched<<<dim3(H / 32, S / 32, B), dim3(32, 8), 0, stream>>>(Vbuf, Vt, S, H);

    // G3: scores = Q @ K^T * scale          [B,1024,2048] bf16
    gemm_nt<false, false, true><<<dim3(S / 128, L / 128, B), 256, 0, stream>>>(
        Abuf, Kbuf, Scores, nullptr, nullptr, H, H, H, S,
        (long)L * H, (long)S * H, (long)L * S, scale);

    // softmax in-place on bf16 scores -> alpha
    softmax2048_bf16<<<B * L, 256, 0, stream>>>(Scores);

    // G5: H_hyper = alpha @ V (NT vs Vt)    [B,1024,1024] bf16 -> Abuf (Q dead)
    gemm_nt<false, false, true><<<dim3(H / 128, L / 128, B), 256, 0, stream>>>(
        Scores, Vt, Abuf, nullptr, nullptr, S, S, S, H,
        (long)L * S, (long)H * S, (long)L * H, 1.0f);

    // G6: out_pre = H_hyper @ W_out + b_out + H_l  [16384,1024] fp32 (K dead)
    gemm_nt<true, true, false><<<dim3(H / 128, B * L / 128, 1), 256, 0, stream>>>(
        Abuf, Wt_out, OutPre, b_out, H_l, H, H, H, H, 0, 0, 0, 1.0f);

    // LN3 -> d_out fp32 (Vt dead)
    ln1024<false, false><<<B * L, 256, 0, stream>>>(OutPre, g_out, beta_out, (float*)d_out);
}

// Round 3
// 660.192 us; speedup vs baseline: 1.0039x; 1.0039x over previous
//
#include <hip/hip_runtime.h>
#include <cstdio>

typedef unsigned short u16;
typedef __bf16 bf16x8 __attribute__((ext_vector_type(8)));
typedef float f32x4 __attribute__((ext_vector_type(4)));
typedef unsigned short us4 __attribute__((ext_vector_type(4)));
typedef unsigned short us8 __attribute__((ext_vector_type(8)));

__device__ __forceinline__ u16 f2bf(float f) {
    union { float f; unsigned u; } x; x.f = f;
    unsigned u = x.u + 0x7fffu + ((x.u >> 16) & 1u);   // RNE
    return (u16)(u >> 16);
}
__device__ __forceinline__ float bf2f(u16 u) {
    union { unsigned u; float f; } x; x.u = ((unsigned)u) << 16;
    return x.f;
}

// ---------------------------------------------------------------------------
// NT GEMM: C[M,N] = A[M,K] * B[N,K]^T, bf16 in, fp32 accumulate.
// 128x128 tile, BK=32, 256 threads (4 waves, 2x2), 16x16x32 bf16 MFMA.
// grid: (N/128, M/128, batch)
//
// Block-index remap (z==1 weight GEMMs only):
//   1) m204 XCD-bijective chunking: XCD k processes a contiguous chunk of
//      remapped ids (HW round-robins original flat id across 8 XCDs).
//   2) band supertiling: remapped ids walk all N-columns of an 8-row M-band
//      before the next band -> per-XCD L2 working set = full W + 8 A-panels
//      (<= 4 MiB) so W is fetched once per band, not once per row-block.
// ---------------------------------------------------------------------------
template<bool HAS_BIAS, bool HAS_RESID, bool OUT_BF16>
__global__ __launch_bounds__(256)
void gemm_nt(const u16* __restrict__ A, const u16* __restrict__ Bm,
             void* __restrict__ Cm, const float* __restrict__ bias,
             const float* __restrict__ resid,
             int K, int lda, int ldb, int ldc,
             long sA, long sB, long sC, float scale)
{
    __shared__ __align__(16) u16 lA[128 * 32];   // [row][k] row-major, 64B row stride
    __shared__ __align__(16) u16 lB[128 * 32];

    const int tid = threadIdx.x;
    const long bz = blockIdx.z;
    A  += bz * sA;
    Bm += bz * sB;
    const long cbase = bz * sC;

    // ---- block-index remap (bijective; requires gy%8==0 && nwg%8==0) ----
    int bx, by;
    if (gridDim.z == 1) {
        const int gx = gridDim.x;
        const int flat = blockIdx.y * gx + blockIdx.x;
        const int q = (gx * gridDim.y) >> 3;       // chunk size per XCD
        const int wg = (flat & 7) * q + (flat >> 3);
        const int per = gx << 3;                   // band = 8 rows x gx cols
        const int band = wg / per, rem = wg % per;
        bx = rem % gx;
        by = band * 8 + rem / gx;
    } else {
        bx = blockIdx.x; by = blockIdx.y;
    }
    const int m0 = by * 128;
    const int n0 = bx * 128;

    const int lane = tid & 63;
    const int w  = tid >> 6;
    const int wr = w >> 1, wc = w & 1;        // wave 64x64 sub-tile
    const int fr = lane & 15;                 // A row / B col within fragment
    const int kg = lane >> 4;                 // k-group (0..3) of 8

    f32x4 acc[4][4] = {};

    const int nk = K >> 5;
    for (int kt = 0; kt < nk; ++kt) {
        // stage A,B tiles: 8KB each via global_load_lds width=16
#pragma unroll
        for (int i = 0; i < 2; ++i) {
            int c = i * 256 + tid;            // chunk 0..511
            int row = c >> 2, seg = c & 3;    // 4x16B per 64B row
            const u16* srcA = A + (long)(m0 + row) * lda + (kt * 32 + seg * 8);
            __builtin_amdgcn_global_load_lds(
                (const __attribute__((address_space(1))) void*)srcA,
                (__attribute__((address_space(3))) void*)(&lA[c * 8]), 16, 0, 0);
            const u16* srcB = Bm + (long)(n0 + row) * ldb + (kt * 32 + seg * 8);
            __builtin_amdgcn_global_load_lds(
                (const __attribute__((address_space(1))) void*)srcB,
                (__attribute__((address_space(3))) void*)(&lB[c * 8]), 16, 0, 0);
        }
        __syncthreads();   // drains vmcnt: staged data visible

        bf16x8 af[4], bfv[4];
#pragma unroll
        for (int mf = 0; mf < 4; ++mf)
            af[mf] = *(const bf16x8*)&lA[(wr * 64 + mf * 16 + fr) * 32 + kg * 8];
#pragma unroll
        for (int nf = 0; nf < 4; ++nf)
            bfv[nf] = *(const bf16x8*)&lB[(wc * 64 + nf * 16 + fr) * 32 + kg * 8];
#pragma unroll
        for (int mf = 0; mf < 4; ++mf)
#pragma unroll
            for (int nf = 0; nf < 4; ++nf)
                acc[mf][nf] = __builtin_amdgcn_mfma_f32_16x16x32_bf16(
                    af[mf], bfv[nf], acc[mf][nf], 0, 0, 0);
        __syncthreads();   // compute done before next stage overwrites
    }

    // epilogue: C/D layout col=lane&15, row=(lane>>4)*4+reg  [m89-verified]
    const int orow = m0 + wr * 64 + kg * 4;
    const int ocol = n0 + wc * 64 + fr;
#pragma unroll
    for (int mf = 0; mf < 4; ++mf) {
#pragma unroll
        for (int r = 0; r < 4; ++r) {
            const int m = orow + mf * 16 + r;
#pragma unroll
            for (int nf = 0; nf < 4; ++nf) {
                const int n = ocol + nf * 16;
                float v = acc[mf][nf][r] * scale;
                if (HAS_BIAS)  v += bias[n];
                if (HAS_RESID) v += resid[cbase + (long)m * ldc + n];
                if (OUT_BF16)  ((u16*)Cm)[cbase + (long)m * ldc + n] = f2bf(v);
                else           ((float*)Cm)[cbase + (long)m * ldc + n] = v;
            }
        }
    }
}

// ---------------------------------------------------------------------------
// LayerNorm over D=1024, one block (256 thr) per row.
// IN_BF16/OUT_BF16 select dtypes. Safe in-place (row read fully before write).
// ---------------------------------------------------------------------------
template<bool IN_BF16, bool OUT_BF16>
__global__ __launch_bounds__(256)
void ln1024(const void* in, const float* __restrict__ g,
            const float* __restrict__ beta, void* out)
{
    const long row = blockIdx.x;
    const int tid = threadIdx.x;
    float x0, x1, x2, x3;
    if (IN_BF16) {
        const us4 v = ((const us4*)in)[row * 256 + tid];
        x0 = bf2f(v[0]); x1 = bf2f(v[1]); x2 = bf2f(v[2]); x3 = bf2f(v[3]);
    } else {
        const float4 v = ((const float4*)in)[row * 256 + tid];
        x0 = v.x; x1 = v.y; x2 = v.z; x3 = v.w;
    }
    float s  = x0 + x1 + x2 + x3;
    float s2 = x0 * x0 + x1 * x1 + x2 * x2 + x3 * x3;
#pragma unroll
    for (int off = 32; off > 0; off >>= 1) {
        s  += __shfl_xor(s, off);
        s2 += __shfl_xor(s2, off);
    }
    __shared__ float rs[4], rq[4];
    if ((tid & 63) == 0) { rs[tid >> 6] = s; rq[tid >> 6] = s2; }
    __syncthreads();
    const float S  = rs[0] + rs[1] + rs[2] + rs[3];
    const float S2 = rq[0] + rq[1] + rq[2] + rq[3];
    const float mu = S * (1.0f / 1024.0f);
    const float var = S2 * (1.0f / 1024.0f) - mu * mu;
    const float rstd = rsqrtf(var + 1e-5f);
    const float4 gg = ((const float4*)g)[tid];
    const float4 bb = ((const float4*)beta)[tid];
    const float y0 = (x0 - mu) * rstd * gg.x + bb.x;
    const float y1 = (x1 - mu) * rstd * gg.y + bb.y;
    const float y2 = (x2 - mu) * rstd * gg.z + bb.z;
    const float y3 = (x3 - mu) * rstd * gg.w + bb.w;
    if (OUT_BF16) {
        us4 o; o[0] = f2bf(y0); o[1] = f2bf(y1); o[2] = f2bf(y2); o[3] = f2bf(y3);
        ((us4*)out)[row * 256 + tid] = o;
    } else {
        float4 o; o.x = y0; o.y = y1; o.z = y2; o.w = y3;
        ((float4*)out)[row * 256 + tid] = o;
    }
}

// ---------------------------------------------------------------------------
// Softmax over width 2048, bf16 in -> bf16 out, IN-PLACE. One block per row.
// ---------------------------------------------------------------------------
__global__ __launch_bounds__(256)
void softmax2048_bf16(u16* io)
{
    const long row = blockIdx.x;
    const int tid = threadIdx.x;
    const us8 v = ((const us8*)io)[row * 256 + tid];
    float x[8];
#pragma unroll
    for (int i = 0; i < 8; ++i) x[i] = bf2f(v[i]);
    float m = x[0];
#pragma unroll
    for (int i = 1; i < 8; ++i) m = fmaxf(m, x[i]);
#pragma unroll
    for (int off = 32; off > 0; off >>= 1) m = fmaxf(m, __shfl_xor(m, off));
    __shared__ float rm[4], rsum[4];
    if ((tid & 63) == 0) rm[tid >> 6] = m;
    __syncthreads();
    m = fmaxf(fmaxf(rm[0], rm[1]), fmaxf(rm[2], rm[3]));
    float e[8];
    float s = 0.f;
#pragma unroll
    for (int i = 0; i < 8; ++i) { e[i] = __expf(x[i] - m); s += e[i]; }
#pragma unroll
    for (int off = 32; off > 0; off >>= 1) s += __shfl_xor(s, off);
    if ((tid & 63) == 0) rsum[tid >> 6] = s;
    __syncthreads();
    s = rsum[0] + rsum[1] + rsum[2] + rsum[3];
    const float inv = 1.0f / s;
    us8 o;
#pragma unroll
    for (int i = 0; i < 8; ++i) o[i] = f2bf(e[i] * inv);
    ((us8*)io)[row * 256 + tid] = o;
}

// fp32 -> bf16 cast, 8 elems/thread
__global__ __launch_bounds__(256)
void cast_f32_bf16(const float* __restrict__ in, u16* __restrict__ out, long n8)
{
    const long i = (long)blockIdx.x * 256 + threadIdx.x;
    if (i >= n8) return;
    const float4 a = ((const float4*)in)[i * 2];
    const float4 b = ((const float4*)in)[i * 2 + 1];
    us8 o;
    o[0] = f2bf(a.x); o[1] = f2bf(a.y); o[2] = f2bf(a.z); o[3] = f2bf(a.w);
    o[4] = f2bf(b.x); o[5] = f2bf(b.y); o[6] = f2bf(b.z); o[7] = f2bf(b.w);
    ((us8*)out)[i] = o;
}

// transpose + cast: fp32 [R,C] -> bf16 [C,R]. block (32,8), grid (C/32, R/32)
__global__ __launch_bounds__(256)
void tcast_f32_bf16(const float* __restrict__ in, u16* __restrict__ out,
                    int R, int C)
{
    __shared__ float t[32][33];
    const int tx = threadIdx.x, ty = threadIdx.y;
    const int c0 = blockIdx.x * 32, r0 = blockIdx.y * 32;
#pragma unroll
    for (int i = 0; i < 4; ++i)
        t[ty + i * 8][tx] = in[(long)(r0 + ty + i * 8) * C + c0 + tx];
    __syncthreads();
#pragma unroll
    for (int i = 0; i < 4; ++i)
        out[(long)(c0 + ty + i * 8) * R + r0 + tx] = f2bf(t[tx][ty + i * 8]);
}

// batched bf16 transpose: [R,C] -> [C,R] per batch. grid (C/32, R/32, batch)
__global__ __launch_bounds__(256)
void t_bf16_batched(const u16* __restrict__ in, u16* __restrict__ out,
                    int R, int C)
{
    __shared__ u16 t[32][34];
    const int tx = threadIdx.x, ty = threadIdx.y;
    const int c0 = blockIdx.x * 32, r0 = blockIdx.y * 32;
    const long base = (long)blockIdx.z * R * C;
#pragma unroll
    for (int i = 0; i < 4; ++i)
        t[ty + i * 8][tx] = in[base + (long)(r0 + ty + i * 8) * C + c0 + tx];
    __syncthreads();
#pragma unroll
    for (int i = 0; i < 4; ++i)
        out[base + (long)(c0 + ty + i * 8) * R + r0 + tx] = t[tx][ty + i * 8];
}

// ---------------------------------------------------------------------------
extern "C" void kernel_launch(void* const* d_in, const int* in_sizes, int n_in,
                              void* d_out, int out_size, void* d_ws, size_t ws_size,
                              hipStream_t stream)
{
    const float* H_l      = (const float*)d_in[0];
    const float* H_a      = (const float*)d_in[1];
    const float* W_text   = (const float*)d_in[2];
    const float* b_text   = (const float*)d_in[3];
    const float* W_audio  = (const float*)d_in[4];
    const float* b_audio  = (const float*)d_in[5];
    const float* W_out    = (const float*)d_in[6];
    const float* b_out    = (const float*)d_in[7];
    const float* g1       = (const float*)d_in[8];
    const float* beta1    = (const float*)d_in[9];
    const float* g2       = (const float*)d_in[10];
    const float* beta2    = (const float*)d_in[11];
    const float* g_out    = (const float*)d_in[12];
    const float* beta_out = (const float*)d_in[13];
    (void)in_sizes; (void)n_in; (void)out_size;

    const int B = 16, L = 1024, S = 2048, DT = 1024, DA = 768, H = 1024;

    // ---------------- workspace layout (~245.5 MiB, heavy overlay) ---------
    // R0 [0, 80Mi):  Hl_bf16(32Mi) + Ha_bf16(48Mi); both dead after G2, then
    //                scores/alpha bf16 (64Mi) overlays from offset 0.
    // A  [80,112Mi): text_p bf16 -> (in-place LN) Q bf16 -> (after G3) Hh bf16
    // C  [112,176Mi): audio_p bf16 (= V)
    // D  [176,240Mi): K bf16 -> (after attn) out_pre fp32 (both exactly 64Mi)
    // W  [240,~245.5Mi): transposed bf16 weights
    // Vt lives in d_out (exactly 64Mi); final LN overwrites all of d_out.
    char* ws = (char*)d_ws;
    const size_t SZ_HLB = (size_t)B * L * DT * 2;          // 33,554,432
    const size_t SZ_HAB = (size_t)B * S * DA * 2;          // 50,331,648
    const size_t O_A    = SZ_HLB + SZ_HAB;                 // 83,886,080
    const size_t SZ_A   = (size_t)B * L * H * 2;           // 33,554,432
    const size_t O_C    = O_A + SZ_A;                      // 117,440,512
    const size_t SZ_C   = (size_t)B * S * H * 2;           // 67,108,864
    const size_t O_D    = O_C + SZ_C;                      // 184,549,376
    const size_t SZ_D   = (size_t)B * S * H * 2;           // 67,108,864 (== B*L*H*4)
    const size_t O_W    = O_D + SZ_D;                      // 251,658,240
    const size_t need   = O_W + (size_t)(DT * H + DA * H + H * H) * 2;

    if (ws_size < need) {
        fprintf(stderr, "[kernel_launch] ws_size=%zu < needed=%zu — aborting launches\n",
                ws_size, need);
        return;
    }

    u16*   Hlb     = (u16*)(ws);                 // dies after G1
    u16*   Hab     = (u16*)(ws + SZ_HLB);        // dies after G2
    u16*   Scores  = (u16*)(ws);                 // born at G3 (overlays Hlb/Hab)
    u16*   Abuf    = (u16*)(ws + O_A);           // text_p -> Q -> Hh
    u16*   Vbuf    = (u16*)(ws + O_C);           // audio_p = V
    u16*   Kbuf    = (u16*)(ws + O_D);           // K
    float* OutPre  = (float*)(ws + O_D);         // out_pre (after K dies)
    u16*   Wt_text  = (u16*)(ws + O_W);
    u16*   Wt_audio = Wt_text + (size_t)DT * H;
    u16*   Wt_out   = Wt_audio + (size_t)DA * H;
    u16*   Vt      = (u16*)d_out;                // 64 MiB, dies before final LN

    const float scale = 0.03125f; // 1/sqrt(1024)

    // input casts to bf16
    cast_f32_bf16<<<(B * L * DT / 8 + 255) / 256, 256, 0, stream>>>(H_l, Hlb, (long)B * L * DT / 8);
    cast_f32_bf16<<<(B * S * DA / 8 + 255) / 256, 256, 0, stream>>>(H_a, Hab, (long)B * S * DA / 8);
    // weight transposes [K,N] -> [N,K] bf16
    tcast_f32_bf16<<<dim3(H / 32, DT / 32), dim3(32, 8), 0, stream>>>(W_text, Wt_text, DT, H);
    tcast_f32_bf16<<<dim3(H / 32, DA / 32), dim3(32, 8), 0, stream>>>(W_audio, Wt_audio, DA, H);
    tcast_f32_bf16<<<dim3(H / 32, H / 32),  dim3(32, 8), 0, stream>>>(W_out, Wt_out, H, H);

    // G1: text_p = H_l @ W_text + b_text   [16384,1024] bf16
    gemm_nt<true, false, true><<<dim3(H / 128, B * L / 128, 1), 256, 0, stream>>>(
        Hlb, Wt_text, Abuf, b_text, nullptr, DT, DT, DT, H, 0, 0, 0, 1.0f);
    // LN1 in-place: text_p -> Q
    ln1024<true, true><<<B * L, 256, 0, stream>>>(Abuf, g1, beta1, Abuf);

    // G2: audio_p = H_a @ W_audio + b_audio [32768,1024] bf16 (= V)
    gemm_nt<true, false, true><<<dim3(H / 128, B * S / 128, 1), 256, 0, stream>>>(
        Hab, Wt_audio, Vbuf, b_audio, nullptr, DA, DA, DA, H, 0, 0, 0, 1.0f);
    // LN2: audio_p -> K
    ln1024<true, true><<<B * S, 256, 0, stream>>>(Vbuf, g2, beta2, Kbuf);

    // V [S,H] -> Vt [H,S] per batch (Vt lives in d_out)
    t_bf16_batched<<<dim3(H / 32, S / 32, B), dim3(32, 8), 0, stream>>>(Vbuf, Vt, S, H);

    // G3: scores = Q @ K^T * scale          [B,1024,2048] bf16
    gemm_nt<false, false, true><<<dim3(S / 128, L / 128, B), 256, 0, stream>>>(
        Abuf, Kbuf, Scores, nullptr, nullptr, H, H, H, S,
        (long)L * H, (long)S * H, (long)L * S, scale);

    // softmax in-place on bf16 scores -> alpha
    softmax2048_bf16<<<B * L, 256, 0, stream>>>(Scores);

    // G5: H_hyper = alpha @ V (NT vs Vt)    [B,1024,1024] bf16 -> Abuf (Q dead)
    gemm_nt<false, false, true><<<dim3(H / 128, L / 128, B), 256, 0, stream>>>(
        Scores, Vt, Abuf, nullptr, nullptr, S, S, S, H,
        (long)L * S, (long)H * S, (long)L * H, 1.0f);

    // G6: out_pre = H_hyper @ W_out + b_out + H_l  [16384,1024] fp32 (K dead)
    gemm_nt<true, true, false><<<dim3(H / 128, B * L / 128, 1), 256, 0, stream>>>(
        Abuf, Wt_out, OutPre, b_out, H_l, H, H, H, H, 0, 0, 0, 1.0f);

    // LN3 -> d_out fp32 (Vt dead)
    ln1024<false, false><<<B * L, 256, 0, stream>>>(OutPre, g_out, beta_out, (float*)d_out);
}

// Round 4
// 642.211 us; speedup vs baseline: 1.0320x; 1.0280x over previous
//
#include <hip/hip_runtime.h>
#include <cstdio>

typedef unsigned short u16;
typedef __bf16 bf16x8 __attribute__((ext_vector_type(8)));
typedef float f32x4 __attribute__((ext_vector_type(4)));
typedef unsigned short us4 __attribute__((ext_vector_type(4)));
typedef unsigned short us8 __attribute__((ext_vector_type(8)));

__device__ __forceinline__ u16 f2bf(float f) {
    union { float f; unsigned u; } x; x.f = f;
    unsigned u = x.u + 0x7fffu + ((x.u >> 16) & 1u);   // RNE
    return (u16)(u >> 16);
}
__device__ __forceinline__ float bf2f(u16 u) {
    union { unsigned u; float f; } x; x.u = ((unsigned)u) << 16;
    return x.f;
}

// ---------------------------------------------------------------------------
// NT GEMM: C[M,N] = A[M,K] * B[N,K]^T, bf16 in, fp32 accumulate.
// 128x128 tile, BK=32, 256 threads (4 waves, 2x2), 16x16x32 bf16 MFMA.
// T3 minimum 2-phase: double-buffered LDS, next-tile global_load_lds issued
// BEFORE current-tile compute, ONE __syncthreads (vmcnt0+lgkmcnt0+barrier)
// per K-step placed AFTER the MFMAs -> stage latency hides under compute.
// TAG distinguishes instances in rocprof.
// grid: (N/128, M/128, batch)
// ---------------------------------------------------------------------------
template<int TAG, bool HAS_BIAS, bool HAS_RESID, bool OUT_BF16>
__global__ __launch_bounds__(256)
void gemm_nt(const u16* __restrict__ A, const u16* __restrict__ Bm,
             void* __restrict__ Cm, const float* __restrict__ bias,
             const float* __restrict__ resid,
             int K, int lda, int ldb, int ldc,
             long sA, long sB, long sC, float scale)
{
    __shared__ __align__(16) u16 lA[2][128 * 32];   // [buf][row][k], 64B rows
    __shared__ __align__(16) u16 lB[2][128 * 32];

    const int tid = threadIdx.x;
    const long bz = blockIdx.z;
    A  += bz * sA;
    Bm += bz * sB;
    const long cbase = bz * sC;

    // ---- block-index remap (bijective; z==1 weight GEMMs only) ----
    int bx, by;
    if (gridDim.z == 1) {
        const int gx = gridDim.x;
        const int flat = blockIdx.y * gx + blockIdx.x;
        const int q = (gx * gridDim.y) >> 3;       // chunk size per XCD
        const int wg = (flat & 7) * q + (flat >> 3);
        const int per = gx << 3;                   // band = 8 rows x gx cols
        const int band = wg / per, rem = wg % per;
        bx = rem % gx;
        by = band * 8 + rem / gx;
    } else {
        bx = blockIdx.x; by = blockIdx.y;
    }
    const int m0 = by * 128;
    const int n0 = bx * 128;

    const int lane = tid & 63;
    const int w  = tid >> 6;
    const int wr = w >> 1, wc = w & 1;        // wave 64x64 sub-tile
    const int fr = lane & 15;                 // A row / B col within fragment
    const int kg = lane >> 4;                 // k-group (0..3) of 8

    f32x4 acc[4][4] = {};

    // per-thread staging coords (2 chunks of 16B per buffer per tile)
    const int c0r = tid >> 2,         c0s = tid & 3;
    const int c1r = (256 + tid) >> 2, c1s = tid & 3;   // (256+tid)&3 == tid&3

    auto stage = [&](int b, int kt) {
        const u16* sA0 = A + (long)(m0 + c0r) * lda + (kt * 32 + c0s * 8);
        __builtin_amdgcn_global_load_lds(
            (const __attribute__((address_space(1))) void*)sA0,
            (__attribute__((address_space(3))) void*)(&lA[b][tid * 8]), 16, 0, 0);
        const u16* sB0 = Bm + (long)(n0 + c0r) * ldb + (kt * 32 + c0s * 8);
        __builtin_amdgcn_global_load_lds(
            (const __attribute__((address_space(1))) void*)sB0,
            (__attribute__((address_space(3))) void*)(&lB[b][tid * 8]), 16, 0, 0);
        const u16* sA1 = A + (long)(m0 + c1r) * lda + (kt * 32 + c1s * 8);
        __builtin_amdgcn_global_load_lds(
            (const __attribute__((address_space(1))) void*)sA1,
            (__attribute__((address_space(3))) void*)(&lA[b][(256 + tid) * 8]), 16, 0, 0);
        const u16* sB1 = Bm + (long)(n0 + c1r) * ldb + (kt * 32 + c1s * 8);
        __builtin_amdgcn_global_load_lds(
            (const __attribute__((address_space(1))) void*)sB1,
            (__attribute__((address_space(3))) void*)(&lB[b][(256 + tid) * 8]), 16, 0, 0);
    };

    const int nk = K >> 5;
    stage(0, 0);
    for (int kt = 0; kt < nk; ++kt) {
        const int b = kt & 1;
        if (kt + 1 < nk) stage(b ^ 1, kt + 1);   // prefetch next tile (other buf)
        if (kt == 0) __syncthreads();            // prologue: wait stage(0)

        bf16x8 af[4], bfv[4];
#pragma unroll
        for (int mf = 0; mf < 4; ++mf)
            af[mf] = *(const bf16x8*)&lA[b][(wr * 64 + mf * 16 + fr) * 32 + kg * 8];
#pragma unroll
        for (int nf = 0; nf < 4; ++nf)
            bfv[nf] = *(const bf16x8*)&lB[b][(wc * 64 + nf * 16 + fr) * 32 + kg * 8];
#pragma unroll
        for (int mf = 0; mf < 4; ++mf)
#pragma unroll
            for (int nf = 0; nf < 4; ++nf)
                acc[mf][nf] = __builtin_amdgcn_mfma_f32_16x16x32_bf16(
                    af[mf], bfv[nf], acc[mf][nf], 0, 0, 0);

        // single barrier per K-step, AFTER compute:
        //  - vmcnt(0): next tile's stage (issued above) has landed
        //  - lgkmcnt(0)+barrier: all waves done reading buf b before it is
        //    overwritten at iteration kt+2
        __syncthreads();
    }

    // epilogue: C/D layout col=lane&15, row=(lane>>4)*4+reg  [m89-verified]
    const int orow = m0 + wr * 64 + kg * 4;
    const int ocol = n0 + wc * 64 + fr;
#pragma unroll
    for (int mf = 0; mf < 4; ++mf) {
#pragma unroll
        for (int r = 0; r < 4; ++r) {
            const int m = orow + mf * 16 + r;
#pragma unroll
            for (int nf = 0; nf < 4; ++nf) {
                const int n = ocol + nf * 16;
                float v = acc[mf][nf][r] * scale;
                if (HAS_BIAS)  v += bias[n];
                if (HAS_RESID) v += resid[cbase + (long)m * ldc + n];
                if (OUT_BF16)  ((u16*)Cm)[cbase + (long)m * ldc + n] = f2bf(v);
                else           ((float*)Cm)[cbase + (long)m * ldc + n] = v;
            }
        }
    }
}

// ---------------------------------------------------------------------------
// LayerNorm over D=1024, one block (256 thr) per row.
// IN_BF16/OUT_BF16 select dtypes. Safe in-place (row read fully before write).
// ---------------------------------------------------------------------------
template<bool IN_BF16, bool OUT_BF16>
__global__ __launch_bounds__(256)
void ln1024(const void* in, const float* __restrict__ g,
            const float* __restrict__ beta, void* out)
{
    const long row = blockIdx.x;
    const int tid = threadIdx.x;
    float x0, x1, x2, x3;
    if (IN_BF16) {
        const us4 v = ((const us4*)in)[row * 256 + tid];
        x0 = bf2f(v[0]); x1 = bf2f(v[1]); x2 = bf2f(v[2]); x3 = bf2f(v[3]);
    } else {
        const float4 v = ((const float4*)in)[row * 256 + tid];
        x0 = v.x; x1 = v.y; x2 = v.z; x3 = v.w;
    }
    float s  = x0 + x1 + x2 + x3;
    float s2 = x0 * x0 + x1 * x1 + x2 * x2 + x3 * x3;
#pragma unroll
    for (int off = 32; off > 0; off >>= 1) {
        s  += __shfl_xor(s, off);
        s2 += __shfl_xor(s2, off);
    }
    __shared__ float rs[4], rq[4];
    if ((tid & 63) == 0) { rs[tid >> 6] = s; rq[tid >> 6] = s2; }
    __syncthreads();
    const float S  = rs[0] + rs[1] + rs[2] + rs[3];
    const float S2 = rq[0] + rq[1] + rq[2] + rq[3];
    const float mu = S * (1.0f / 1024.0f);
    const float var = S2 * (1.0f / 1024.0f) - mu * mu;
    const float rstd = rsqrtf(var + 1e-5f);
    const float4 gg = ((const float4*)g)[tid];
    const float4 bb = ((const float4*)beta)[tid];
    const float y0 = (x0 - mu) * rstd * gg.x + bb.x;
    const float y1 = (x1 - mu) * rstd * gg.y + bb.y;
    const float y2 = (x2 - mu) * rstd * gg.z + bb.z;
    const float y3 = (x3 - mu) * rstd * gg.w + bb.w;
    if (OUT_BF16) {
        us4 o; o[0] = f2bf(y0); o[1] = f2bf(y1); o[2] = f2bf(y2); o[3] = f2bf(y3);
        ((us4*)out)[row * 256 + tid] = o;
    } else {
        float4 o; o.x = y0; o.y = y1; o.z = y2; o.w = y3;
        ((float4*)out)[row * 256 + tid] = o;
    }
}

// ---------------------------------------------------------------------------
// Softmax over width 2048, bf16 in -> bf16 out, IN-PLACE. One block per row.
// ---------------------------------------------------------------------------
__global__ __launch_bounds__(256)
void softmax2048_bf16(u16* io)
{
    const long row = blockIdx.x;
    const int tid = threadIdx.x;
    const us8 v = ((const us8*)io)[row * 256 + tid];
    float x[8];
#pragma unroll
    for (int i = 0; i < 8; ++i) x[i] = bf2f(v[i]);
    float m = x[0];
#pragma unroll
    for (int i = 1; i < 8; ++i) m = fmaxf(m, x[i]);
#pragma unroll
    for (int off = 32; off > 0; off >>= 1) m = fmaxf(m, __shfl_xor(m, off));
    __shared__ float rm[4], rsum[4];
    if ((tid & 63) == 0) rm[tid >> 6] = m;
    __syncthreads();
    m = fmaxf(fmaxf(rm[0], rm[1]), fmaxf(rm[2], rm[3]));
    float e[8];
    float s = 0.f;
#pragma unroll
    for (int i = 0; i < 8; ++i) { e[i] = __expf(x[i] - m); s += e[i]; }
#pragma unroll
    for (int off = 32; off > 0; off >>= 1) s += __shfl_xor(s, off);
    if ((tid & 63) == 0) rsum[tid >> 6] = s;
    __syncthreads();
    s = rsum[0] + rsum[1] + rsum[2] + rsum[3];
    const float inv = 1.0f / s;
    us8 o;
#pragma unroll
    for (int i = 0; i < 8; ++i) o[i] = f2bf(e[i] * inv);
    ((us8*)io)[row * 256 + tid] = o;
}

// fp32 -> bf16 cast, 8 elems/thread
__global__ __launch_bounds__(256)
void cast_f32_bf16(const float* __restrict__ in, u16* __restrict__ out, long n8)
{
    const long i = (long)blockIdx.x * 256 + threadIdx.x;
    if (i >= n8) return;
    const float4 a = ((const float4*)in)[i * 2];
    const float4 b = ((const float4*)in)[i * 2 + 1];
    us8 o;
    o[0] = f2bf(a.x); o[1] = f2bf(a.y); o[2] = f2bf(a.z); o[3] = f2bf(a.w);
    o[4] = f2bf(b.x); o[5] = f2bf(b.y); o[6] = f2bf(b.z); o[7] = f2bf(b.w);
    ((us8*)out)[i] = o;
}

// transpose + cast: fp32 [R,C] -> bf16 [C,R]. block (32,8), grid (C/32, R/32)
__global__ __launch_bounds__(256)
void tcast_f32_bf16(const float* __restrict__ in, u16* __restrict__ out,
                    int R, int C)
{
    __shared__ float t[32][33];
    const int tx = threadIdx.x, ty = threadIdx.y;
    const int c0 = blockIdx.x * 32, r0 = blockIdx.y * 32;
#pragma unroll
    for (int i = 0; i < 4; ++i)
        t[ty + i * 8][tx] = in[(long)(r0 + ty + i * 8) * C + c0 + tx];
    __syncthreads();
#pragma unroll
    for (int i = 0; i < 4; ++i)
        out[(long)(c0 + ty + i * 8) * R + r0 + tx] = f2bf(t[tx][ty + i * 8]);
}

// batched bf16 transpose: [R,C] -> [C,R] per batch. grid (C/32, R/32, batch)
__global__ __launch_bounds__(256)
void t_bf16_batched(const u16* __restrict__ in, u16* __restrict__ out,
                    int R, int C)
{
    __shared__ u16 t[32][34];
    const int tx = threadIdx.x, ty = threadIdx.y;
    const int c0 = blockIdx.x * 32, r0 = blockIdx.y * 32;
    const long base = (long)blockIdx.z * R * C;
#pragma unroll
    for (int i = 0; i < 4; ++i)
        t[ty + i * 8][tx] = in[base + (long)(r0 + ty + i * 8) * C + c0 + tx];
    __syncthreads();
#pragma unroll
    for (int i = 0; i < 4; ++i)
        out[base + (long)(c0 + ty + i * 8) * R + r0 + tx] = t[tx][ty + i * 8];
}

// ---------------------------------------------------------------------------
extern "C" void kernel_launch(void* const* d_in, const int* in_sizes, int n_in,
                              void* d_out, int out_size, void* d_ws, size_t ws_size,
                              hipStream_t stream)
{
    const float* H_l      = (const float*)d_in[0];
    const float* H_a      = (const float*)d_in[1];
    const float* W_text   = (const float*)d_in[2];
    const float* b_text   = (const float*)d_in[3];
    const float* W_audio  = (const float*)d_in[4];
    const float* b_audio  = (const float*)d_in[5];
    const float* W_out    = (const float*)d_in[6];
    const float* b_out    = (const float*)d_in[7];
    const float* g1       = (const float*)d_in[8];
    const float* beta1    = (const float*)d_in[9];
    const float* g2       = (const float*)d_in[10];
    const float* beta2    = (const float*)d_in[11];
    const float* g_out    = (const float*)d_in[12];
    const float* beta_out = (const float*)d_in[13];
    (void)in_sizes; (void)n_in; (void)out_size;

    const int B = 16, L = 1024, S = 2048, DT = 1024, DA = 768, H = 1024;

    // ---------------- workspace layout (~245.5 MiB, heavy overlay) ---------
    char* ws = (char*)d_ws;
    const size_t SZ_HLB = (size_t)B * L * DT * 2;          // 33,554,432
    const size_t SZ_HAB = (size_t)B * S * DA * 2;          // 50,331,648
    const size_t O_A    = SZ_HLB + SZ_HAB;                 // 83,886,080
    const size_t SZ_A   = (size_t)B * L * H * 2;           // 33,554,432
    const size_t O_C    = O_A + SZ_A;                      // 117,440,512
    const size_t SZ_C   = (size_t)B * S * H * 2;           // 67,108,864
    const size_t O_D    = O_C + SZ_C;                      // 184,549,376
    const size_t SZ_D   = (size_t)B * S * H * 2;           // 67,108,864 (== B*L*H*4)
    const size_t O_W    = O_D + SZ_D;                      // 251,658,240
    const size_t need   = O_W + (size_t)(DT * H + DA * H + H * H) * 2;

    if (ws_size < need) {
        fprintf(stderr, "[kernel_launch] ws_size=%zu < needed=%zu — aborting launches\n",
                ws_size, need);
        return;
    }

    u16*   Hlb     = (u16*)(ws);                 // dies after G1
    u16*   Hab     = (u16*)(ws + SZ_HLB);        // dies after G2
    u16*   Scores  = (u16*)(ws);                 // born at G3 (overlays Hlb/Hab)
    u16*   Abuf    = (u16*)(ws + O_A);           // text_p -> Q -> Hh
    u16*   Vbuf    = (u16*)(ws + O_C);           // audio_p = V
    u16*   Kbuf    = (u16*)(ws + O_D);           // K
    float* OutPre  = (float*)(ws + O_D);         // out_pre (after K dies)
    u16*   Wt_text  = (u16*)(ws + O_W);
    u16*   Wt_audio = Wt_text + (size_t)DT * H;
    u16*   Wt_out   = Wt_audio + (size_t)DA * H;
    u16*   Vt      = (u16*)d_out;                // 64 MiB, dies before final LN

    const float scale = 0.03125f; // 1/sqrt(1024)

    // input casts to bf16
    cast_f32_bf16<<<(B * L * DT / 8 + 255) / 256, 256, 0, stream>>>(H_l, Hlb, (long)B * L * DT / 8);
    cast_f32_bf16<<<(B * S * DA / 8 + 255) / 256, 256, 0, stream>>>(H_a, Hab, (long)B * S * DA / 8);
    // weight transposes [K,N] -> [N,K] bf16
    tcast_f32_bf16<<<dim3(H / 32, DT / 32), dim3(32, 8), 0, stream>>>(W_text, Wt_text, DT, H);
    tcast_f32_bf16<<<dim3(H / 32, DA / 32), dim3(32, 8), 0, stream>>>(W_audio, Wt_audio, DA, H);
    tcast_f32_bf16<<<dim3(H / 32, H / 32),  dim3(32, 8), 0, stream>>>(W_out, Wt_out, H, H);

    // G1: text_p = H_l @ W_text + b_text   [16384,1024] bf16
    gemm_nt<1, true, false, true><<<dim3(H / 128, B * L / 128, 1), 256, 0, stream>>>(
        Hlb, Wt_text, Abuf, b_text, nullptr, DT, DT, DT, H, 0, 0, 0, 1.0f);
    // LN1 in-place: text_p -> Q
    ln1024<true, true><<<B * L, 256, 0, stream>>>(Abuf, g1, beta1, Abuf);

    // G2: audio_p = H_a @ W_audio + b_audio [32768,1024] bf16 (= V)
    gemm_nt<2, true, false, true><<<dim3(H / 128, B * S / 128, 1), 256, 0, stream>>>(
        Hab, Wt_audio, Vbuf, b_audio, nullptr, DA, DA, DA, H, 0, 0, 0, 1.0f);
    // LN2: audio_p -> K
    ln1024<true, true><<<B * S, 256, 0, stream>>>(Vbuf, g2, beta2, Kbuf);

    // V [S,H] -> Vt [H,S] per batch (Vt lives in d_out)
    t_bf16_batched<<<dim3(H / 32, S / 32, B), dim3(32, 8), 0, stream>>>(Vbuf, Vt, S, H);

    // G3: scores = Q @ K^T * scale          [B,1024,2048] bf16
    gemm_nt<3, false, false, true><<<dim3(S / 128, L / 128, B), 256, 0, stream>>>(
        Abuf, Kbuf, Scores, nullptr, nullptr, H, H, H, S,
        (long)L * H, (long)S * H, (long)L * S, scale);

    // softmax in-place on bf16 scores -> alpha
    softmax2048_bf16<<<B * L, 256, 0, stream>>>(Scores);

    // G5: H_hyper = alpha @ V (NT vs Vt)    [B,1024,1024] bf16 -> Abuf (Q dead)
    gemm_nt<5, false, false, true><<<dim3(H / 128, L / 128, B), 256, 0, stream>>>(
        Scores, Vt, Abuf, nullptr, nullptr, S, S, S, H,
        (long)L * S, (long)H * S, (long)L * H, 1.0f);

    // G6: out_pre = H_hyper @ W_out + b_out + H_l  [16384,1024] fp32 (K dead)
    gemm_nt<6, true, true, false><<<dim3(H / 128, B * L / 128, 1), 256, 0, stream>>>(
        Abuf, Wt_out, OutPre, b_out, H_l, H, H, H, H, 0, 0, 0, 1.0f);

    // LN3 -> d_out fp32 (Vt dead)
    ln1024<false, false><<<B * L, 256, 0, stream>>>(OutPre, g_out, beta_out, (float*)d_out);
}

// Round 5
// 615.355 us; speedup vs baseline: 1.0770x; 1.0436x over previous
//
#include <hip/hip_runtime.h>
#include <cstdio>

typedef unsigned short u16;
typedef __bf16 bf16x8 __attribute__((ext_vector_type(8)));
typedef float f32x4 __attribute__((ext_vector_type(4)));
typedef unsigned short us4 __attribute__((ext_vector_type(4)));
typedef unsigned short us8 __attribute__((ext_vector_type(8)));

__device__ __forceinline__ u16 f2bf(float f) {
    union { float f; unsigned u; } x; x.f = f;
    unsigned u = x.u + 0x7fffu + ((x.u >> 16) & 1u);   // RNE
    return (u16)(u >> 16);
}
__device__ __forceinline__ float bf2f(u16 u) {
    union { unsigned u; float f; } x; x.u = ((unsigned)u) << 16;
    return x.f;
}

// ---------------------------------------------------------------------------
// NT GEMM: C[M,N] = A[M,K] * B[N,K]^T, bf16 in, fp32 accumulate.
// 256x256 tile (halves ideal-miss HBM traffic vs 128²), BK=32, 512 threads
// (8 waves, 2Mx4N; per-wave 128x64 output), 16x16x32 bf16 MFMA.
// 2-phase: double-buffered LDS, next-tile global_load_lds issued BEFORE
// current-tile compute, ONE __syncthreads (vmcnt0+lgkmcnt0+barrier) per
// K-step AFTER the MFMAs. grid: (N/256, M/256, batch)
// ---------------------------------------------------------------------------
template<int TAG, bool HAS_BIAS, bool HAS_RESID, bool OUT_BF16>
__global__ __launch_bounds__(512)
void gemm_nt(const u16* __restrict__ A, const u16* __restrict__ Bm,
             void* __restrict__ Cm, const float* __restrict__ bias,
             const float* __restrict__ resid,
             int K, int lda, int ldb, int ldc,
             long sA, long sB, long sC, float scale)
{
    __shared__ __align__(16) u16 lA[2][256 * 32];   // [buf][row][k], 64B rows
    __shared__ __align__(16) u16 lB[2][256 * 32];   // total 64 KiB

    const int tid = threadIdx.x;
    const long bz = blockIdx.z;
    A  += bz * sA;
    Bm += bz * sB;
    const long cbase = bz * sC;

    // ---- block-index remap (bijective; z==1 weight GEMMs only) ----
    int bx, by;
    if (gridDim.z == 1) {
        const int gx = gridDim.x;
        const int flat = blockIdx.y * gx + blockIdx.x;
        const int q = (gx * gridDim.y) >> 3;       // chunk size per XCD
        const int wg = (flat & 7) * q + (flat >> 3);
        const int per = gx << 3;                   // band = 8 rows x gx cols
        const int band = wg / per, rem = wg % per;
        bx = rem % gx;
        by = band * 8 + rem / gx;
    } else {
        bx = blockIdx.x; by = blockIdx.y;
    }
    const int m0 = by * 256;
    const int n0 = bx * 256;

    const int lane = tid & 63;
    const int w  = tid >> 6;                  // wave 0..7
    const int wr = w >> 2, wc = w & 3;        // 2x4 wave grid, 128x64 per wave
    const int fr = lane & 15;                 // A row / B col within fragment
    const int kg = lane >> 4;                 // k-group (0..3) of 8

    f32x4 acc[8][4] = {};

    // staging: per K-step 16 KiB per operand = 1024 16B-chunks; 512 thr x2
    auto stage = [&](int b, int kt) {
#pragma unroll
        for (int h = 0; h < 2; ++h) {
            const int c = h * 512 + tid;
            const int row = c >> 2, seg = c & 3;   // 4x16B per 64B row
            const u16* sAp = A + (long)(m0 + row) * lda + (kt * 32 + seg * 8);
            __builtin_amdgcn_global_load_lds(
                (const __attribute__((address_space(1))) void*)sAp,
                (__attribute__((address_space(3))) void*)(&lA[b][c * 8]), 16, 0, 0);
            const u16* sBp = Bm + (long)(n0 + row) * ldb + (kt * 32 + seg * 8);
            __builtin_amdgcn_global_load_lds(
                (const __attribute__((address_space(1))) void*)sBp,
                (__attribute__((address_space(3))) void*)(&lB[b][c * 8]), 16, 0, 0);
        }
    };

    const int nk = K >> 5;
    stage(0, 0);
    for (int kt = 0; kt < nk; ++kt) {
        const int b = kt & 1;
        if (kt + 1 < nk) stage(b ^ 1, kt + 1);   // prefetch next tile (other buf)
        if (kt == 0) __syncthreads();            // prologue: wait stage(0)

        bf16x8 af[8], bfv[4];
#pragma unroll
        for (int mf = 0; mf < 8; ++mf)
            af[mf] = *(const bf16x8*)&lA[b][(wr * 128 + mf * 16 + fr) * 32 + kg * 8];
#pragma unroll
        for (int nf = 0; nf < 4; ++nf)
            bfv[nf] = *(const bf16x8*)&lB[b][(wc * 64 + nf * 16 + fr) * 32 + kg * 8];
#pragma unroll
        for (int mf = 0; mf < 8; ++mf)
#pragma unroll
            for (int nf = 0; nf < 4; ++nf)
                acc[mf][nf] = __builtin_amdgcn_mfma_f32_16x16x32_bf16(
                    af[mf], bfv[nf], acc[mf][nf], 0, 0, 0);

        // single barrier per K-step, AFTER compute:
        //  - vmcnt(0): next tile's stage (issued above) has landed
        //  - lgkmcnt(0)+barrier: all waves done reading buf b before it is
        //    overwritten at iteration kt+2
        __syncthreads();
    }

    // epilogue: C/D layout col=lane&15, row=(lane>>4)*4+reg  [m89-verified]
    const int orow = m0 + wr * 128 + kg * 4;
    const int ocol = n0 + wc * 64 + fr;
#pragma unroll
    for (int mf = 0; mf < 8; ++mf) {
#pragma unroll
        for (int r = 0; r < 4; ++r) {
            const int m = orow + mf * 16 + r;
#pragma unroll
            for (int nf = 0; nf < 4; ++nf) {
                const int n = ocol + nf * 16;
                float v = acc[mf][nf][r] * scale;
                if (HAS_BIAS)  v += bias[n];
                if (HAS_RESID) v += resid[cbase + (long)m * ldc + n];
                if (OUT_BF16)  ((u16*)Cm)[cbase + (long)m * ldc + n] = f2bf(v);
                else           ((float*)Cm)[cbase + (long)m * ldc + n] = v;
            }
        }
    }
}

// ---------------------------------------------------------------------------
// LayerNorm over D=1024, one block (256 thr) per row.
// IN_BF16/OUT_BF16 select dtypes. Safe in-place (row read fully before write).
// ---------------------------------------------------------------------------
template<bool IN_BF16, bool OUT_BF16>
__global__ __launch_bounds__(256)
void ln1024(const void* in, const float* __restrict__ g,
            const float* __restrict__ beta, void* out)
{
    const long row = blockIdx.x;
    const int tid = threadIdx.x;
    float x0, x1, x2, x3;
    if (IN_BF16) {
        const us4 v = ((const us4*)in)[row * 256 + tid];
        x0 = bf2f(v[0]); x1 = bf2f(v[1]); x2 = bf2f(v[2]); x3 = bf2f(v[3]);
    } else {
        const float4 v = ((const float4*)in)[row * 256 + tid];
        x0 = v.x; x1 = v.y; x2 = v.z; x3 = v.w;
    }
    float s  = x0 + x1 + x2 + x3;
    float s2 = x0 * x0 + x1 * x1 + x2 * x2 + x3 * x3;
#pragma unroll
    for (int off = 32; off > 0; off >>= 1) {
        s  += __shfl_xor(s, off);
        s2 += __shfl_xor(s2, off);
    }
    __shared__ float rs[4], rq[4];
    if ((tid & 63) == 0) { rs[tid >> 6] = s; rq[tid >> 6] = s2; }
    __syncthreads();
    const float S  = rs[0] + rs[1] + rs[2] + rs[3];
    const float S2 = rq[0] + rq[1] + rq[2] + rq[3];
    const float mu = S * (1.0f / 1024.0f);
    const float var = S2 * (1.0f / 1024.0f) - mu * mu;
    const float rstd = rsqrtf(var + 1e-5f);
    const float4 gg = ((const float4*)g)[tid];
    const float4 bb = ((const float4*)beta)[tid];
    const float y0 = (x0 - mu) * rstd * gg.x + bb.x;
    const float y1 = (x1 - mu) * rstd * gg.y + bb.y;
    const float y2 = (x2 - mu) * rstd * gg.z + bb.z;
    const float y3 = (x3 - mu) * rstd * gg.w + bb.w;
    if (OUT_BF16) {
        us4 o; o[0] = f2bf(y0); o[1] = f2bf(y1); o[2] = f2bf(y2); o[3] = f2bf(y3);
        ((us4*)out)[row * 256 + tid] = o;
    } else {
        float4 o; o.x = y0; o.y = y1; o.z = y2; o.w = y3;
        ((float4*)out)[row * 256 + tid] = o;
    }
}

// ---------------------------------------------------------------------------
// Softmax over width 2048, bf16 in -> bf16 out, IN-PLACE. One block per row.
// ---------------------------------------------------------------------------
__global__ __launch_bounds__(256)
void softmax2048_bf16(u16* io)
{
    const long row = blockIdx.x;
    const int tid = threadIdx.x;
    const us8 v = ((const us8*)io)[row * 256 + tid];
    float x[8];
#pragma unroll
    for (int i = 0; i < 8; ++i) x[i] = bf2f(v[i]);
    float m = x[0];
#pragma unroll
    for (int i = 1; i < 8; ++i) m = fmaxf(m, x[i]);
#pragma unroll
    for (int off = 32; off > 0; off >>= 1) m = fmaxf(m, __shfl_xor(m, off));
    __shared__ float rm[4], rsum[4];
    if ((tid & 63) == 0) rm[tid >> 6] = m;
    __syncthreads();
    m = fmaxf(fmaxf(rm[0], rm[1]), fmaxf(rm[2], rm[3]));
    float e[8];
    float s = 0.f;
#pragma unroll
    for (int i = 0; i < 8; ++i) { e[i] = __expf(x[i] - m); s += e[i]; }
#pragma unroll
    for (int off = 32; off > 0; off >>= 1) s += __shfl_xor(s, off);
    if ((tid & 63) == 0) rsum[tid >> 6] = s;
    __syncthreads();
    s = rsum[0] + rsum[1] + rsum[2] + rsum[3];
    const float inv = 1.0f / s;
    us8 o;
#pragma unroll
    for (int i = 0; i < 8; ++i) o[i] = f2bf(e[i] * inv);
    ((us8*)io)[row * 256 + tid] = o;
}

// fp32 -> bf16 cast, 8 elems/thread
__global__ __launch_bounds__(256)
void cast_f32_bf16(const float* __restrict__ in, u16* __restrict__ out, long n8)
{
    const long i = (long)blockIdx.x * 256 + threadIdx.x;
    if (i >= n8) return;
    const float4 a = ((const float4*)in)[i * 2];
    const float4 b = ((const float4*)in)[i * 2 + 1];
    us8 o;
    o[0] = f2bf(a.x); o[1] = f2bf(a.y); o[2] = f2bf(a.z); o[3] = f2bf(a.w);
    o[4] = f2bf(b.x); o[5] = f2bf(b.y); o[6] = f2bf(b.z); o[7] = f2bf(b.w);
    ((us8*)out)[i] = o;
}

// transpose + cast: fp32 [R,C] -> bf16 [C,R]. block (32,8), grid (C/32, R/32)
__global__ __launch_bounds__(256)
void tcast_f32_bf16(const float* __restrict__ in, u16* __restrict__ out,
                    int R, int C)
{
    __shared__ float t[32][33];
    const int tx = threadIdx.x, ty = threadIdx.y;
    const int c0 = blockIdx.x * 32, r0 = blockIdx.y * 32;
#pragma unroll
    for (int i = 0; i < 4; ++i)
        t[ty + i * 8][tx] = in[(long)(r0 + ty + i * 8) * C + c0 + tx];
    __syncthreads();
#pragma unroll
    for (int i = 0; i < 4; ++i)
        out[(long)(c0 + ty + i * 8) * R + r0 + tx] = f2bf(t[tx][ty + i * 8]);
}

// batched bf16 transpose: [R,C] -> [C,R] per batch. grid (C/32, R/32, batch)
__global__ __launch_bounds__(256)
void t_bf16_batched(const u16* __restrict__ in, u16* __restrict__ out,
                    int R, int C)
{
    __shared__ u16 t[32][34];
    const int tx = threadIdx.x, ty = threadIdx.y;
    const int c0 = blockIdx.x * 32, r0 = blockIdx.y * 32;
    const long base = (long)blockIdx.z * R * C;
#pragma unroll
    for (int i = 0; i < 4; ++i)
        t[ty + i * 8][tx] = in[base + (long)(r0 + ty + i * 8) * C + c0 + tx];
    __syncthreads();
#pragma unroll
    for (int i = 0; i < 4; ++i)
        out[base + (long)(c0 + ty + i * 8) * R + r0 + tx] = t[tx][ty + i * 8];
}

// ---------------------------------------------------------------------------
extern "C" void kernel_launch(void* const* d_in, const int* in_sizes, int n_in,
                              void* d_out, int out_size, void* d_ws, size_t ws_size,
                              hipStream_t stream)
{
    const float* H_l      = (const float*)d_in[0];
    const float* H_a      = (const float*)d_in[1];
    const float* W_text   = (const float*)d_in[2];
    const float* b_text   = (const float*)d_in[3];
    const float* W_audio  = (const float*)d_in[4];
    const float* b_audio  = (const float*)d_in[5];
    const float* W_out    = (const float*)d_in[6];
    const float* b_out    = (const float*)d_in[7];
    const float* g1       = (const float*)d_in[8];
    const float* beta1    = (const float*)d_in[9];
    const float* g2       = (const float*)d_in[10];
    const float* beta2    = (const float*)d_in[11];
    const float* g_out    = (const float*)d_in[12];
    const float* beta_out = (const float*)d_in[13];
    (void)in_sizes; (void)n_in; (void)out_size;

    const int B = 16, L = 1024, S = 2048, DT = 1024, DA = 768, H = 1024;

    // ---------------- workspace layout (~245.5 MiB, heavy overlay) ---------
    char* ws = (char*)d_ws;
    const size_t SZ_HLB = (size_t)B * L * DT * 2;          // 33,554,432
    const size_t SZ_HAB = (size_t)B * S * DA * 2;          // 50,331,648
    const size_t O_A    = SZ_HLB + SZ_HAB;                 // 83,886,080
    const size_t SZ_A   = (size_t)B * L * H * 2;           // 33,554,432
    const size_t O_C    = O_A + SZ_A;                      // 117,440,512
    const size_t SZ_C   = (size_t)B * S * H * 2;           // 67,108,864
    const size_t O_D    = O_C + SZ_C;                      // 184,549,376
    const size_t SZ_D   = (size_t)B * S * H * 2;           // 67,108,864 (== B*L*H*4)
    const size_t O_W    = O_D + SZ_D;                      // 251,658,240
    const size_t need   = O_W + (size_t)(DT * H + DA * H + H * H) * 2;

    if (ws_size < need) {
        fprintf(stderr, "[kernel_launch] ws_size=%zu < needed=%zu — aborting launches\n",
                ws_size, need);
        return;
    }

    u16*   Hlb     = (u16*)(ws);                 // dies after G1
    u16*   Hab     = (u16*)(ws + SZ_HLB);        // dies after G2
    u16*   Scores  = (u16*)(ws);                 // born at G3 (overlays Hlb/Hab)
    u16*   Abuf    = (u16*)(ws + O_A);           // text_p -> Q -> Hh
    u16*   Vbuf    = (u16*)(ws + O_C);           // audio_p = V
    u16*   Kbuf    = (u16*)(ws + O_D);           // K
    float* OutPre  = (float*)(ws + O_D);         // out_pre (after K dies)
    u16*   Wt_text  = (u16*)(ws + O_W);
    u16*   Wt_audio = Wt_text + (size_t)DT * H;
    u16*   Wt_out   = Wt_audio + (size_t)DA * H;
    u16*   Vt      = (u16*)d_out;                // 64 MiB, dies before final LN

    const float scale = 0.03125f; // 1/sqrt(1024)

    // input casts to bf16
    cast_f32_bf16<<<(B * L * DT / 8 + 255) / 256, 256, 0, stream>>>(H_l, Hlb, (long)B * L * DT / 8);
    cast_f32_bf16<<<(B * S * DA / 8 + 255) / 256, 256, 0, stream>>>(H_a, Hab, (long)B * S * DA / 8);
    // weight transposes [K,N] -> [N,K] bf16
    tcast_f32_bf16<<<dim3(H / 32, DT / 32), dim3(32, 8), 0, stream>>>(W_text, Wt_text, DT, H);
    tcast_f32_bf16<<<dim3(H / 32, DA / 32), dim3(32, 8), 0, stream>>>(W_audio, Wt_audio, DA, H);
    tcast_f32_bf16<<<dim3(H / 32, H / 32),  dim3(32, 8), 0, stream>>>(W_out, Wt_out, H, H);

    // G1: text_p = H_l @ W_text + b_text   [16384,1024] bf16
    gemm_nt<1, true, false, true><<<dim3(H / 256, B * L / 256, 1), 512, 0, stream>>>(
        Hlb, Wt_text, Abuf, b_text, nullptr, DT, DT, DT, H, 0, 0, 0, 1.0f);
    // LN1 in-place: text_p -> Q
    ln1024<true, true><<<B * L, 256, 0, stream>>>(Abuf, g1, beta1, Abuf);

    // G2: audio_p = H_a @ W_audio + b_audio [32768,1024] bf16 (= V)
    gemm_nt<2, true, false, true><<<dim3(H / 256, B * S / 256, 1), 512, 0, stream>>>(
        Hab, Wt_audio, Vbuf, b_audio, nullptr, DA, DA, DA, H, 0, 0, 0, 1.0f);
    // LN2: audio_p -> K
    ln1024<true, true><<<B * S, 256, 0, stream>>>(Vbuf, g2, beta2, Kbuf);

    // V [S,H] -> Vt [H,S] per batch (Vt lives in d_out)
    t_bf16_batched<<<dim3(H / 32, S / 32, B), dim3(32, 8), 0, stream>>>(Vbuf, Vt, S, H);

    // G3: scores = Q @ K^T * scale          [B,1024,2048] bf16
    gemm_nt<3, false, false, true><<<dim3(S / 256, L / 256, B), 512, 0, stream>>>(
        Abuf, Kbuf, Scores, nullptr, nullptr, H, H, H, S,
        (long)L * H, (long)S * H, (long)L * S, scale);

    // softmax in-place on bf16 scores -> alpha
    softmax2048_bf16<<<B * L, 256, 0, stream>>>(Scores);

    // G5: H_hyper = alpha @ V (NT vs Vt)    [B,1024,1024] bf16 -> Abuf (Q dead)
    gemm_nt<5, false, false, true><<<dim3(H / 256, L / 256, B), 512, 0, stream>>>(
        Scores, Vt, Abuf, nullptr, nullptr, S, S, S, H,
        (long)L * S, (long)H * S, (long)L * H, 1.0f);

    // G6: out_pre = H_hyper @ W_out + b_out + H_l  [16384,1024] fp32 (K dead)
    gemm_nt<6, true, true, false><<<dim3(H / 256, B * L / 256, 1), 512, 0, stream>>>(
        Abuf, Wt_out, OutPre, b_out, H_l, H, H, H, H, 0, 0, 0, 1.0f);

    // LN3 -> d_out fp32 (Vt dead)
    ln1024<false, false><<<B * L, 256, 0, stream>>>(OutPre, g_out, beta_out, (float*)d_out);
}

// Round 6
// 588.892 us; speedup vs baseline: 1.1254x; 1.0449x over previous
//
#include <hip/hip_runtime.h>
#include <cstdio>

typedef unsigned short u16;
typedef __bf16 bf16x8 __attribute__((ext_vector_type(8)));
typedef float f32x4 __attribute__((ext_vector_type(4)));
typedef unsigned short us4 __attribute__((ext_vector_type(4)));
typedef unsigned short us8 __attribute__((ext_vector_type(8)));

__device__ __forceinline__ u16 f2bf(float f) {
    union { float f; unsigned u; } x; x.f = f;
    unsigned u = x.u + 0x7fffu + ((x.u >> 16) & 1u);   // RNE
    return (u16)(u >> 16);
}
__device__ __forceinline__ float bf2f(u16 u) {
    union { unsigned u; float f; } x; x.u = ((unsigned)u) << 16;
    return x.f;
}

// ---------------------------------------------------------------------------
// NT GEMM: C[M,N] = A[M,K] * B[N,K]^T, bf16 in, fp32 accumulate.
// 256x256 tile, BK=32, 512 threads (8 waves, 2Mx4N; 128x64 per wave),
// 16x16x32 bf16 MFMA.
// T4 counted-vmcnt 3-deep pipeline: 3 LDS buffers (96 KiB), stage(t+2)
// issued at iter t, s_waitcnt vmcnt(8) (= 2 stages x 4 loads in flight)
// guarantees stage(t) landed; raw s_barrier (no vmcnt(0) drain in loop).
// Hazards: RAW global->LDS via vmcnt(N)+barrier1 (all waves passed their own
// wait); RAW LDS->MFMA via compiler lgkmcnt; WAR: buf[t%3] rewritten by
// stage(t+3) at iter t+1, issued after iter t's barrier2 which follows all
// reads of buf[t%3]. grid: (N/256, M/256, batch)
// ---------------------------------------------------------------------------
template<int TAG, bool HAS_BIAS, bool HAS_RESID, bool OUT_BF16>
__global__ __launch_bounds__(512)
void gemm_nt(const u16* __restrict__ A, const u16* __restrict__ Bm,
             void* __restrict__ Cm, const float* __restrict__ bias,
             const float* __restrict__ resid,
             int K, int lda, int ldb, int ldc,
             long sA, long sB, long sC, float scale)
{
    __shared__ __align__(16) u16 lA[3][256 * 32];   // [buf][row][k], 64B rows
    __shared__ __align__(16) u16 lB[3][256 * 32];   // total 96 KiB

    const int tid = threadIdx.x;
    const long bz = blockIdx.z;
    A  += bz * sA;
    Bm += bz * sB;
    const long cbase = bz * sC;

    // ---- block-index remap (bijective; z==1 weight GEMMs only) ----
    int bx, by;
    if (gridDim.z == 1) {
        const int gx = gridDim.x;
        const int flat = blockIdx.y * gx + blockIdx.x;
        const int q = (gx * gridDim.y) >> 3;       // chunk size per XCD
        const int wg = (flat & 7) * q + (flat >> 3);
        const int per = gx << 3;                   // band = 8 rows x gx cols
        const int band = wg / per, rem = wg % per;
        bx = rem % gx;
        by = band * 8 + rem / gx;
    } else {
        bx = blockIdx.x; by = blockIdx.y;
    }
    const int m0 = by * 256;
    const int n0 = bx * 256;

    const int lane = tid & 63;
    const int w  = tid >> 6;                  // wave 0..7
    const int wr = w >> 2, wc = w & 3;        // 2x4 wave grid, 128x64 per wave
    const int fr = lane & 15;                 // A row / B col within fragment
    const int kg = lane >> 4;                 // k-group (0..3) of 8

    f32x4 acc[8][4] = {};

    // staging: per K-step 16 KiB per operand = 1024 16B-chunks; 512 thr x2
    // -> 4 global_load_lds per thread per stage (vmcnt counts 4 per stage)
    auto stage = [&](int b, int kt) {
#pragma unroll
        for (int h = 0; h < 2; ++h) {
            const int c = h * 512 + tid;
            const int row = c >> 2, seg = c & 3;   // 4x16B per 64B row
            const u16* sAp = A + (long)(m0 + row) * lda + (kt * 32 + seg * 8);
            __builtin_amdgcn_global_load_lds(
                (const __attribute__((address_space(1))) void*)sAp,
                (__attribute__((address_space(3))) void*)(&lA[b][c * 8]), 16, 0, 0);
            const u16* sBp = Bm + (long)(n0 + row) * ldb + (kt * 32 + seg * 8);
            __builtin_amdgcn_global_load_lds(
                (const __attribute__((address_space(1))) void*)sBp,
                (__attribute__((address_space(3))) void*)(&lB[b][c * 8]), 16, 0, 0);
        }
    };

    const int nk = K >> 5;                 // all K here are multiples of 32, nk >= 24
    stage(0, 0);
    stage(1, 1);
    for (int kt = 0; kt < nk; ++kt) {
        const int b = kt % 3;
        if (kt + 2 < nk) {
            stage((kt + 2) % 3, kt + 2);   // keep 2 stages in flight
            asm volatile("s_waitcnt vmcnt(8)" ::: "memory");  // stage(kt) landed
        } else if (kt + 1 < nk) {
            asm volatile("s_waitcnt vmcnt(4)" ::: "memory");
        } else {
            asm volatile("s_waitcnt vmcnt(0)" ::: "memory");
        }
        __builtin_amdgcn_s_barrier();      // all waves' stage(kt) visible
        asm volatile("" ::: "memory");

        bf16x8 af[8], bfv[4];
#pragma unroll
        for (int mf = 0; mf < 8; ++mf)
            af[mf] = *(const bf16x8*)&lA[b][(wr * 128 + mf * 16 + fr) * 32 + kg * 8];
#pragma unroll
        for (int nf = 0; nf < 4; ++nf)
            bfv[nf] = *(const bf16x8*)&lB[b][(wc * 64 + nf * 16 + fr) * 32 + kg * 8];

        __builtin_amdgcn_s_setprio(1);
#pragma unroll
        for (int mf = 0; mf < 8; ++mf)
#pragma unroll
            for (int nf = 0; nf < 4; ++nf)
                acc[mf][nf] = __builtin_amdgcn_mfma_f32_16x16x32_bf16(
                    af[mf], bfv[nf], acc[mf][nf], 0, 0, 0);
        __builtin_amdgcn_s_setprio(0);

        asm volatile("" ::: "memory");
        __builtin_amdgcn_s_barrier();      // all reads of buf b done before
        asm volatile("" ::: "memory");     // stage(kt+3) overwrites it
    }

    // epilogue: C/D layout col=lane&15, row=(lane>>4)*4+reg  [m89-verified]
    const int orow = m0 + wr * 128 + kg * 4;
    const int ocol = n0 + wc * 64 + fr;
#pragma unroll
    for (int mf = 0; mf < 8; ++mf) {
#pragma unroll
        for (int r = 0; r < 4; ++r) {
            const int m = orow + mf * 16 + r;
#pragma unroll
            for (int nf = 0; nf < 4; ++nf) {
                const int n = ocol + nf * 16;
                float v = acc[mf][nf][r] * scale;
                if (HAS_BIAS)  v += bias[n];
                if (HAS_RESID) v += resid[cbase + (long)m * ldc + n];
                if (OUT_BF16)  ((u16*)Cm)[cbase + (long)m * ldc + n] = f2bf(v);
                else           ((float*)Cm)[cbase + (long)m * ldc + n] = v;
            }
        }
    }
}

// ---------------------------------------------------------------------------
// LayerNorm over D=1024, one block (256 thr) per row.
// IN_BF16/OUT_BF16 select dtypes. Safe in-place (row read fully before write).
// ---------------------------------------------------------------------------
template<bool IN_BF16, bool OUT_BF16>
__global__ __launch_bounds__(256)
void ln1024(const void* in, const float* __restrict__ g,
            const float* __restrict__ beta, void* out)
{
    const long row = blockIdx.x;
    const int tid = threadIdx.x;
    float x0, x1, x2, x3;
    if (IN_BF16) {
        const us4 v = ((const us4*)in)[row * 256 + tid];
        x0 = bf2f(v[0]); x1 = bf2f(v[1]); x2 = bf2f(v[2]); x3 = bf2f(v[3]);
    } else {
        const float4 v = ((const float4*)in)[row * 256 + tid];
        x0 = v.x; x1 = v.y; x2 = v.z; x3 = v.w;
    }
    float s  = x0 + x1 + x2 + x3;
    float s2 = x0 * x0 + x1 * x1 + x2 * x2 + x3 * x3;
#pragma unroll
    for (int off = 32; off > 0; off >>= 1) {
        s  += __shfl_xor(s, off);
        s2 += __shfl_xor(s2, off);
    }
    __shared__ float rs[4], rq[4];
    if ((tid & 63) == 0) { rs[tid >> 6] = s; rq[tid >> 6] = s2; }
    __syncthreads();
    const float S  = rs[0] + rs[1] + rs[2] + rs[3];
    const float S2 = rq[0] + rq[1] + rq[2] + rq[3];
    const float mu = S * (1.0f / 1024.0f);
    const float var = S2 * (1.0f / 1024.0f) - mu * mu;
    const float rstd = rsqrtf(var + 1e-5f);
    const float4 gg = ((const float4*)g)[tid];
    const float4 bb = ((const float4*)beta)[tid];
    const float y0 = (x0 - mu) * rstd * gg.x + bb.x;
    const float y1 = (x1 - mu) * rstd * gg.y + bb.y;
    const float y2 = (x2 - mu) * rstd * gg.z + bb.z;
    const float y3 = (x3 - mu) * rstd * gg.w + bb.w;
    if (OUT_BF16) {
        us4 o; o[0] = f2bf(y0); o[1] = f2bf(y1); o[2] = f2bf(y2); o[3] = f2bf(y3);
        ((us4*)out)[row * 256 + tid] = o;
    } else {
        float4 o; o.x = y0; o.y = y1; o.z = y2; o.w = y3;
        ((float4*)out)[row * 256 + tid] = o;
    }
}

// ---------------------------------------------------------------------------
// Softmax over width 2048, bf16 in -> bf16 out, IN-PLACE. One block per row.
// ---------------------------------------------------------------------------
__global__ __launch_bounds__(256)
void softmax2048_bf16(u16* io)
{
    const long row = blockIdx.x;
    const int tid = threadIdx.x;
    const us8 v = ((const us8*)io)[row * 256 + tid];
    float x[8];
#pragma unroll
    for (int i = 0; i < 8; ++i) x[i] = bf2f(v[i]);
    float m = x[0];
#pragma unroll
    for (int i = 1; i < 8; ++i) m = fmaxf(m, x[i]);
#pragma unroll
    for (int off = 32; off > 0; off >>= 1) m = fmaxf(m, __shfl_xor(m, off));
    __shared__ float rm[4], rsum[4];
    if ((tid & 63) == 0) rm[tid >> 6] = m;
    __syncthreads();
    m = fmaxf(fmaxf(rm[0], rm[1]), fmaxf(rm[2], rm[3]));
    float e[8];
    float s = 0.f;
#pragma unroll
    for (int i = 0; i < 8; ++i) { e[i] = __expf(x[i] - m); s += e[i]; }
#pragma unroll
    for (int off = 32; off > 0; off >>= 1) s += __shfl_xor(s, off);
    if ((tid & 63) == 0) rsum[tid >> 6] = s;
    __syncthreads();
    s = rsum[0] + rsum[1] + rsum[2] + rsum[3];
    const float inv = 1.0f / s;
    us8 o;
#pragma unroll
    for (int i = 0; i < 8; ++i) o[i] = f2bf(e[i] * inv);
    ((us8*)io)[row * 256 + tid] = o;
}

// fp32 -> bf16 cast, 8 elems/thread
__global__ __launch_bounds__(256)
void cast_f32_bf16(const float* __restrict__ in, u16* __restrict__ out, long n8)
{
    const long i = (long)blockIdx.x * 256 + threadIdx.x;
    if (i >= n8) return;
    const float4 a = ((const float4*)in)[i * 2];
    const float4 b = ((const float4*)in)[i * 2 + 1];
    us8 o;
    o[0] = f2bf(a.x); o[1] = f2bf(a.y); o[2] = f2bf(a.z); o[3] = f2bf(a.w);
    o[4] = f2bf(b.x); o[5] = f2bf(b.y); o[6] = f2bf(b.z); o[7] = f2bf(b.w);
    ((us8*)out)[i] = o;
}

// transpose + cast: fp32 [R,C] -> bf16 [C,R]. block (32,8), grid (C/32, R/32)
__global__ __launch_bounds__(256)
void tcast_f32_bf16(const float* __restrict__ in, u16* __restrict__ out,
                    int R, int C)
{
    __shared__ float t[32][33];
    const int tx = threadIdx.x, ty = threadIdx.y;
    const int c0 = blockIdx.x * 32, r0 = blockIdx.y * 32;
#pragma unroll
    for (int i = 0; i < 4; ++i)
        t[ty + i * 8][tx] = in[(long)(r0 + ty + i * 8) * C + c0 + tx];
    __syncthreads();
#pragma unroll
    for (int i = 0; i < 4; ++i)
        out[(long)(c0 + ty + i * 8) * R + r0 + tx] = f2bf(t[tx][ty + i * 8]);
}

// batched bf16 transpose: [R,C] -> [C,R] per batch. grid (C/32, R/32, batch)
__global__ __launch_bounds__(256)
void t_bf16_batched(const u16* __restrict__ in, u16* __restrict__ out,
                    int R, int C)
{
    __shared__ u16 t[32][34];
    const int tx = threadIdx.x, ty = threadIdx.y;
    const int c0 = blockIdx.x * 32, r0 = blockIdx.y * 32;
    const long base = (long)blockIdx.z * R * C;
#pragma unroll
    for (int i = 0; i < 4; ++i)
        t[ty + i * 8][tx] = in[base + (long)(r0 + ty + i * 8) * C + c0 + tx];
    __syncthreads();
#pragma unroll
    for (int i = 0; i < 4; ++i)
        out[base + (long)(c0 + ty + i * 8) * R + r0 + tx] = t[tx][ty + i * 8];
}

// ---------------------------------------------------------------------------
extern "C" void kernel_launch(void* const* d_in, const int* in_sizes, int n_in,
                              void* d_out, int out_size, void* d_ws, size_t ws_size,
                              hipStream_t stream)
{
    const float* H_l      = (const float*)d_in[0];
    const float* H_a      = (const float*)d_in[1];
    const float* W_text   = (const float*)d_in[2];
    const float* b_text   = (const float*)d_in[3];
    const float* W_audio  = (const float*)d_in[4];
    const float* b_audio  = (const float*)d_in[5];
    const float* W_out    = (const float*)d_in[6];
    const float* b_out    = (const float*)d_in[7];
    const float* g1       = (const float*)d_in[8];
    const float* beta1    = (const float*)d_in[9];
    const float* g2       = (const float*)d_in[10];
    const float* beta2    = (const float*)d_in[11];
    const float* g_out    = (const float*)d_in[12];
    const float* beta_out = (const float*)d_in[13];
    (void)in_sizes; (void)n_in; (void)out_size;

    const int B = 16, L = 1024, S = 2048, DT = 1024, DA = 768, H = 1024;

    // ---------------- workspace layout (~245.5 MiB, heavy overlay) ---------
    char* ws = (char*)d_ws;
    const size_t SZ_HLB = (size_t)B * L * DT * 2;          // 33,554,432
    const size_t SZ_HAB = (size_t)B * S * DA * 2;          // 50,331,648
    const size_t O_A    = SZ_HLB + SZ_HAB;                 // 83,886,080
    const size_t SZ_A   = (size_t)B * L * H * 2;           // 33,554,432
    const size_t O_C    = O_A + SZ_A;                      // 117,440,512
    const size_t SZ_C   = (size_t)B * S * H * 2;           // 67,108,864
    const size_t O_D    = O_C + SZ_C;                      // 184,549,376
    const size_t SZ_D   = (size_t)B * S * H * 2;           // 67,108,864 (== B*L*H*4)
    const size_t O_W    = O_D + SZ_D;                      // 251,658,240
    const size_t need   = O_W + (size_t)(DT * H + DA * H + H * H) * 2;

    if (ws_size < need) {
        fprintf(stderr, "[kernel_launch] ws_size=%zu < needed=%zu — aborting launches\n",
                ws_size, need);
        return;
    }

    u16*   Hlb     = (u16*)(ws);                 // dies after G1
    u16*   Hab     = (u16*)(ws + SZ_HLB);        // dies after G2
    u16*   Scores  = (u16*)(ws);                 // born at G3 (overlays Hlb/Hab)
    u16*   Abuf    = (u16*)(ws + O_A);           // text_p -> Q -> Hh
    u16*   Vbuf    = (u16*)(ws + O_C);           // audio_p = V
    u16*   Kbuf    = (u16*)(ws + O_D);           // K
    float* OutPre  = (float*)(ws + O_D);         // out_pre (after K dies)
    u16*   Wt_text  = (u16*)(ws + O_W);
    u16*   Wt_audio = Wt_text + (size_t)DT * H;
    u16*   Wt_out   = Wt_audio + (size_t)DA * H;
    u16*   Vt      = (u16*)d_out;                // 64 MiB, dies before final LN

    const float scale = 0.03125f; // 1/sqrt(1024)

    // input casts to bf16
    cast_f32_bf16<<<(B * L * DT / 8 + 255) / 256, 256, 0, stream>>>(H_l, Hlb, (long)B * L * DT / 8);
    cast_f32_bf16<<<(B * S * DA / 8 + 255) / 256, 256, 0, stream>>>(H_a, Hab, (long)B * S * DA / 8);
    // weight transposes [K,N] -> [N,K] bf16
    tcast_f32_bf16<<<dim3(H / 32, DT / 32), dim3(32, 8), 0, stream>>>(W_text, Wt_text, DT, H);
    tcast_f32_bf16<<<dim3(H / 32, DA / 32), dim3(32, 8), 0, stream>>>(W_audio, Wt_audio, DA, H);
    tcast_f32_bf16<<<dim3(H / 32, H / 32),  dim3(32, 8), 0, stream>>>(W_out, Wt_out, H, H);

    // G1: text_p = H_l @ W_text + b_text   [16384,1024] bf16
    gemm_nt<1, true, false, true><<<dim3(H / 256, B * L / 256, 1), 512, 0, stream>>>(
        Hlb, Wt_text, Abuf, b_text, nullptr, DT, DT, DT, H, 0, 0, 0, 1.0f);
    // LN1 in-place: text_p -> Q
    ln1024<true, true><<<B * L, 256, 0, stream>>>(Abuf, g1, beta1, Abuf);

    // G2: audio_p = H_a @ W_audio + b_audio [32768,1024] bf16 (= V)
    gemm_nt<2, true, false, true><<<dim3(H / 256, B * S / 256, 1), 512, 0, stream>>>(
        Hab, Wt_audio, Vbuf, b_audio, nullptr, DA, DA, DA, H, 0, 0, 0, 1.0f);
    // LN2: audio_p -> K
    ln1024<true, true><<<B * S, 256, 0, stream>>>(Vbuf, g2, beta2, Kbuf);

    // V [S,H] -> Vt [H,S] per batch (Vt lives in d_out)
    t_bf16_batched<<<dim3(H / 32, S / 32, B), dim3(32, 8), 0, stream>>>(Vbuf, Vt, S, H);

    // G3: scores = Q @ K^T * scale          [B,1024,2048] bf16
    gemm_nt<3, false, false, true><<<dim3(S / 256, L / 256, B), 512, 0, stream>>>(
        Abuf, Kbuf, Scores, nullptr, nullptr, H, H, H, S,
        (long)L * H, (long)S * H, (long)L * S, scale);

    // softmax in-place on bf16 scores -> alpha
    softmax2048_bf16<<<B * L, 256, 0, stream>>>(Scores);

    // G5: H_hyper = alpha @ V (NT vs Vt)    [B,1024,1024] bf16 -> Abuf (Q dead)
    gemm_nt<5, false, false, true><<<dim3(H / 256, L / 256, B), 512, 0, stream>>>(
        Scores, Vt, Abuf, nullptr, nullptr, S, S, S, H,
        (long)L * S, (long)H * S, (long)L * H, 1.0f);

    // G6: out_pre = H_hyper @ W_out + b_out + H_l  [16384,1024] fp32 (K dead)
    gemm_nt<6, true, true, false><<<dim3(H / 256, B * L / 256, 1), 512, 0, stream>>>(
        Abuf, Wt_out, OutPre, b_out, H_l, H, H, H, H, 0, 0, 0, 1.0f);

    // LN3 -> d_out fp32 (Vt dead)
    ln1024<false, false><<<B * L, 256, 0, stream>>>(OutPre, g_out, beta_out, (float*)d_out);
}

// Round 7
// 578.406 us; speedup vs baseline: 1.1458x; 1.0181x over previous
//
#include <hip/hip_runtime.h>
#include <cstdio>

typedef unsigned short u16;
typedef __bf16 bf16x8 __attribute__((ext_vector_type(8)));
typedef float f32x4 __attribute__((ext_vector_type(4)));
typedef unsigned short us4 __attribute__((ext_vector_type(4)));
typedef unsigned short us8 __attribute__((ext_vector_type(8)));

__device__ __forceinline__ u16 f2bf(float f) {
    union { float f; unsigned u; } x; x.f = f;
    unsigned u = x.u + 0x7fffu + ((x.u >> 16) & 1u);   // RNE
    return (u16)(u >> 16);
}
__device__ __forceinline__ float bf2f(u16 u) {
    union { unsigned u; float f; } x; x.u = ((unsigned)u) << 16;
    return x.f;
}

// ---------------------------------------------------------------------------
// NT GEMM: C[M,N] = A[M,K] * B[N,K]^T, bf16 in, fp32 accumulate.
// 256x256 tile, BK=64, 512 threads (8 waves 2Mx4N, 128x64 per wave).
// 8-phase-style schedule (4 phases per K-tile):
//   each phase: {stage / ds_read} ; s_barrier ; lgkmcnt(0)+sched_barrier ;
//               setprio(1) ; 16 MFMA (one C-quadrant x K=64) ; setprio(0) ;
//               s_barrier.
// Counted waits: the only vmcnt(0) sits in phase 4, where the waited loads
// were issued 6-7 phases earlier (never a mid-flight drain).
// LDS: 2 bufs x (A 32KB + B 32KB) = 128 KiB, XOR-swizzled rows
// (phys_koff = koff ^ ((row&7)<<4)); stage pre-swizzles the GLOBAL source so
// the linear global_load_lds dest + swizzled ds_read agree (both-sides rule).
// Hazard ledger:
//   RAW global->LDS: phase-4 vmcnt(0) + trailing barrier precede T+1's reads.
//   WAR: stage(T+1) writes buf d^1, last read by K-tile T-1 whose ds_reads
//        completed before T-1's phase-4 barriers (lgkmcnt before its MFMAs).
//   RAW LDS->MFMA: lgkmcnt(0) + sched_barrier(0) after each lead barrier.
// grid: (N/256, M/256, batch)
// ---------------------------------------------------------------------------

#define LDFRAG(base, row, koff) \
  (*(const bf16x8*)((const char*)(base) + (size_t)(row) * 128 + \
                    ((koff) ^ (((row) & 7) << 4))))

#define LOAD_A(QM) do { \
  _Pragma("unroll") for (int j = 0; j < 4; ++j) \
    _Pragma("unroll") for (int ks = 0; ks < 2; ++ks) \
      af[j][ks] = LDFRAG(pA, wr * 128 + (QM) * 64 + j * 16 + fr, ks * 64 + kg * 16); \
} while (0)

#define LOAD_B(QN) do { \
  _Pragma("unroll") for (int i = 0; i < 2; ++i) \
    _Pragma("unroll") for (int ks = 0; ks < 2; ++ks) \
      bfr[QN][i][ks] = LDFRAG(pB, wc * 64 + (QN) * 32 + i * 16 + fr, ks * 64 + kg * 16); \
} while (0)

#define MFMA_Q(QM, QN) do { \
  _Pragma("unroll") for (int j = 0; j < 4; ++j) \
    _Pragma("unroll") for (int i = 0; i < 2; ++i) \
      _Pragma("unroll") for (int ks = 0; ks < 2; ++ks) \
        acc[(QM) * 4 + j][(QN) * 2 + i] = __builtin_amdgcn_mfma_f32_16x16x32_bf16( \
            af[j][ks], bfr[QN][i][ks], acc[(QM) * 4 + j][(QN) * 2 + i], 0, 0, 0); \
} while (0)

#define PHASE_SYNC() do { \
  __builtin_amdgcn_s_barrier(); \
  asm volatile("s_waitcnt lgkmcnt(0)" ::: "memory"); \
  __builtin_amdgcn_sched_barrier(0); \
} while (0)

template<int TAG, bool HAS_BIAS, bool HAS_RESID, bool OUT_BF16>
__global__ __launch_bounds__(512, 2)
void gemm_nt(const u16* __restrict__ A, const u16* __restrict__ Bm,
             void* __restrict__ Cm, const float* __restrict__ bias,
             const float* __restrict__ resid,
             int K, int lda, int ldb, int ldc,
             long sA, long sB, long sC, float scale)
{
    // [buf][256 rows][64 elem] per operand; rows are 128B, XOR-swizzled.
    __shared__ __align__(16) u16 lA[2 * 256 * 64];   // 64 KiB
    __shared__ __align__(16) u16 lB[2 * 256 * 64];   // 64 KiB

    const int tid = threadIdx.x;
    const long bz = blockIdx.z;
    A  += bz * sA;
    Bm += bz * sB;
    const long cbase = bz * sC;

    // ---- block-index remap (bijective; z==1 weight GEMMs only) ----
    int bx, by;
    if (gridDim.z == 1) {
        const int gx = gridDim.x;
        const int flat = blockIdx.y * gx + blockIdx.x;
        const int q = (gx * gridDim.y) >> 3;
        const int wg = (flat & 7) * q + (flat >> 3);
        const int per = gx << 3;
        const int band = wg / per, rem = wg % per;
        bx = rem % gx;
        by = band * 8 + rem / gx;
    } else {
        bx = blockIdx.x; by = blockIdx.y;
    }
    const int m0 = by * 256;
    const int n0 = bx * 256;

    const int lane = tid & 63;
    const int w  = tid >> 6;                  // wave 0..7
    const int wr = w >> 2, wc = w & 3;        // 2x4 wave grid, 128x64 per wave
    const int fr = lane & 15;                 // A row / B col within fragment
    const int kg = lane >> 4;                 // k-group (0..3)

    // stage one half-tile (128 rows x 64 K = 16 KB) of operand op, half h,
    // K-tile kt, into buf d_. Global source pre-swizzled; LDS dest linear.
    auto stage_half = [&](int d_, int kt, int op, int h) {
        const u16* src = op ? Bm : A;
        const int  ld  = op ? ldb : lda;
        const int  bs  = op ? n0 : m0;
        u16* lds = (op ? lB : lA) + d_ * 16384 + h * 8192;
#pragma unroll
        for (int i2 = 0; i2 < 2; ++i2) {
            const int c  = i2 * 512 + tid;            // 16B chunk id, 0..1023
            const int r  = c >> 3;                    // row within half
            const int kb = ((c & 7) * 16) ^ ((r & 7) << 4);   // pre-swizzled k byte
            const u16* g = src + (size_t)(bs + h * 128 + r) * ld + kt * 64 + (kb >> 1);
            __builtin_amdgcn_global_load_lds(
                (const __attribute__((address_space(1))) void*)g,
                (__attribute__((address_space(3))) void*)(lds + (size_t)c * 8), 16, 0, 0);
        }
    };

    f32x4 acc[8][4] = {};
    bf16x8 af[4][2];
    bf16x8 bfr[2][2][2];

    const int nt = K >> 6;
    // prologue: stage K-tile 0 fully, drain once
    stage_half(0, 0, 0, 0); stage_half(0, 0, 0, 1);
    stage_half(0, 0, 1, 0); stage_half(0, 0, 1, 1);
    asm volatile("s_waitcnt vmcnt(0)" ::: "memory");
    __builtin_amdgcn_s_barrier();

    for (int T = 0; T < nt; ++T) {
        const int d = T & 1;
        const u16* pA = lA + d * 16384;
        const u16* pB = lB + d * 16384;
        const bool pre = (T + 1 < nt);

        // ---- phase 1: quadrant (0,0); stage A halves of T+1
        if (pre) { stage_half(d ^ 1, T + 1, 0, 0); stage_half(d ^ 1, T + 1, 0, 1); }
        LOAD_A(0); LOAD_B(0);                         // 12 ds_read_b128
        PHASE_SYNC();
        __builtin_amdgcn_s_setprio(1); MFMA_Q(0, 0); __builtin_amdgcn_s_setprio(0);
        __builtin_amdgcn_s_barrier();

        // ---- phase 2: quadrant (0,1); stage B halves of T+1
        if (pre) { stage_half(d ^ 1, T + 1, 1, 0); stage_half(d ^ 1, T + 1, 1, 1); }
        LOAD_B(1);                                    // 4 ds_read_b128
        PHASE_SYNC();
        __builtin_amdgcn_s_setprio(1); MFMA_Q(0, 1); __builtin_amdgcn_s_setprio(0);
        __builtin_amdgcn_s_barrier();

        // ---- phase 3: quadrant (1,0)  (bfr[0] kept in regs)
        LOAD_A(1);                                    // 8 ds_read_b128
        PHASE_SYNC();
        __builtin_amdgcn_s_setprio(1); MFMA_Q(1, 0); __builtin_amdgcn_s_setprio(0);
        __builtin_amdgcn_s_barrier();

        // ---- phase 4: quadrant (1,1)  (register-only); T+1 landed check
        PHASE_SYNC();
        __builtin_amdgcn_s_setprio(1); MFMA_Q(1, 1); __builtin_amdgcn_s_setprio(0);
        if (pre) asm volatile("s_waitcnt vmcnt(0)" ::: "memory");  // issued 6-7 phases ago
        __builtin_amdgcn_s_barrier();
    }

    // epilogue: C/D layout col=lane&15, row=(lane>>4)*4+reg  [m89-verified]
    const int orow = m0 + wr * 128 + kg * 4;
    const int ocol = n0 + wc * 64 + fr;
#pragma unroll
    for (int mf = 0; mf < 8; ++mf) {
#pragma unroll
        for (int r = 0; r < 4; ++r) {
            const int m = orow + mf * 16 + r;
#pragma unroll
            for (int nf = 0; nf < 4; ++nf) {
                const int n = ocol + nf * 16;
                float v = acc[mf][nf][r] * scale;
                if (HAS_BIAS)  v += bias[n];
                if (HAS_RESID) v += resid[cbase + (long)m * ldc + n];
                if (OUT_BF16)  ((u16*)Cm)[cbase + (long)m * ldc + n] = f2bf(v);
                else           ((float*)Cm)[cbase + (long)m * ldc + n] = v;
            }
        }
    }
}

// ---------------------------------------------------------------------------
// LayerNorm over D=1024, one block (256 thr) per row.
// ---------------------------------------------------------------------------
template<bool IN_BF16, bool OUT_BF16>
__global__ __launch_bounds__(256)
void ln1024(const void* in, const float* __restrict__ g,
            const float* __restrict__ beta, void* out)
{
    const long row = blockIdx.x;
    const int tid = threadIdx.x;
    float x0, x1, x2, x3;
    if (IN_BF16) {
        const us4 v = ((const us4*)in)[row * 256 + tid];
        x0 = bf2f(v[0]); x1 = bf2f(v[1]); x2 = bf2f(v[2]); x3 = bf2f(v[3]);
    } else {
        const float4 v = ((const float4*)in)[row * 256 + tid];
        x0 = v.x; x1 = v.y; x2 = v.z; x3 = v.w;
    }
    float s  = x0 + x1 + x2 + x3;
    float s2 = x0 * x0 + x1 * x1 + x2 * x2 + x3 * x3;
#pragma unroll
    for (int off = 32; off > 0; off >>= 1) {
        s  += __shfl_xor(s, off);
        s2 += __shfl_xor(s2, off);
    }
    __shared__ float rs[4], rq[4];
    if ((tid & 63) == 0) { rs[tid >> 6] = s; rq[tid >> 6] = s2; }
    __syncthreads();
    const float S  = rs[0] + rs[1] + rs[2] + rs[3];
    const float S2 = rq[0] + rq[1] + rq[2] + rq[3];
    const float mu = S * (1.0f / 1024.0f);
    const float var = S2 * (1.0f / 1024.0f) - mu * mu;
    const float rstd = rsqrtf(var + 1e-5f);
    const float4 gg = ((const float4*)g)[tid];
    const float4 bb = ((const float4*)beta)[tid];
    const float y0 = (x0 - mu) * rstd * gg.x + bb.x;
    const float y1 = (x1 - mu) * rstd * gg.y + bb.y;
    const float y2 = (x2 - mu) * rstd * gg.z + bb.z;
    const float y3 = (x3 - mu) * rstd * gg.w + bb.w;
    if (OUT_BF16) {
        us4 o; o[0] = f2bf(y0); o[1] = f2bf(y1); o[2] = f2bf(y2); o[3] = f2bf(y3);
        ((us4*)out)[row * 256 + tid] = o;
    } else {
        float4 o; o.x = y0; o.y = y1; o.z = y2; o.w = y3;
        ((float4*)out)[row * 256 + tid] = o;
    }
}

// ---------------------------------------------------------------------------
// Softmax over width 2048, bf16 in/out, IN-PLACE. One block per row.
// ---------------------------------------------------------------------------
__global__ __launch_bounds__(256)
void softmax2048_bf16(u16* io)
{
    const long row = blockIdx.x;
    const int tid = threadIdx.x;
    const us8 v = ((const us8*)io)[row * 256 + tid];
    float x[8];
#pragma unroll
    for (int i = 0; i < 8; ++i) x[i] = bf2f(v[i]);
    float m = x[0];
#pragma unroll
    for (int i = 1; i < 8; ++i) m = fmaxf(m, x[i]);
#pragma unroll
    for (int off = 32; off > 0; off >>= 1) m = fmaxf(m, __shfl_xor(m, off));
    __shared__ float rm[4], rsum[4];
    if ((tid & 63) == 0) rm[tid >> 6] = m;
    __syncthreads();
    m = fmaxf(fmaxf(rm[0], rm[1]), fmaxf(rm[2], rm[3]));
    float e[8];
    float s = 0.f;
#pragma unroll
    for (int i = 0; i < 8; ++i) { e[i] = __expf(x[i] - m); s += e[i]; }
#pragma unroll
    for (int off = 32; off > 0; off >>= 1) s += __shfl_xor(s, off);
    if ((tid & 63) == 0) rsum[tid >> 6] = s;
    __syncthreads();
    s = rsum[0] + rsum[1] + rsum[2] + rsum[3];
    const float inv = 1.0f / s;
    us8 o;
#pragma unroll
    for (int i = 0; i < 8; ++i) o[i] = f2bf(e[i] * inv);
    ((us8*)io)[row * 256 + tid] = o;
}

// fp32 -> bf16 cast, 8 elems/thread
__global__ __launch_bounds__(256)
void cast_f32_bf16(const float* __restrict__ in, u16* __restrict__ out, long n8)
{
    const long i = (long)blockIdx.x * 256 + threadIdx.x;
    if (i >= n8) return;
    const float4 a = ((const float4*)in)[i * 2];
    const float4 b = ((const float4*)in)[i * 2 + 1];
    us8 o;
    o[0] = f2bf(a.x); o[1] = f2bf(a.y); o[2] = f2bf(a.z); o[3] = f2bf(a.w);
    o[4] = f2bf(b.x); o[5] = f2bf(b.y); o[6] = f2bf(b.z); o[7] = f2bf(b.w);
    ((us8*)out)[i] = o;
}

// transpose + cast: fp32 [R,C] -> bf16 [C,R]. block (32,8), grid (C/32, R/32)
__global__ __launch_bounds__(256)
void tcast_f32_bf16(const float* __restrict__ in, u16* __restrict__ out,
                    int R, int C)
{
    __shared__ float t[32][33];
    const int tx = threadIdx.x, ty = threadIdx.y;
    const int c0 = blockIdx.x * 32, r0 = blockIdx.y * 32;
#pragma unroll
    for (int i = 0; i < 4; ++i)
        t[ty + i * 8][tx] = in[(long)(r0 + ty + i * 8) * C + c0 + tx];
    __syncthreads();
#pragma unroll
    for (int i = 0; i < 4; ++i)
        out[(long)(c0 + ty + i * 8) * R + r0 + tx] = f2bf(t[tx][ty + i * 8]);
}

// batched bf16 transpose: [R,C] -> [C,R] per batch. grid (C/32, R/32, batch)
__global__ __launch_bounds__(256)
void t_bf16_batched(const u16* __restrict__ in, u16* __restrict__ out,
                    int R, int C)
{
    __shared__ u16 t[32][34];
    const int tx = threadIdx.x, ty = threadIdx.y;
    const int c0 = blockIdx.x * 32, r0 = blockIdx.y * 32;
    const long base = (long)blockIdx.z * R * C;
#pragma unroll
    for (int i = 0; i < 4; ++i)
        t[ty + i * 8][tx] = in[base + (long)(r0 + ty + i * 8) * C + c0 + tx];
    __syncthreads();
#pragma unroll
    for (int i = 0; i < 4; ++i)
        out[base + (long)(c0 + ty + i * 8) * R + r0 + tx] = t[tx][ty + i * 8];
}

// ---------------------------------------------------------------------------
extern "C" void kernel_launch(void* const* d_in, const int* in_sizes, int n_in,
                              void* d_out, int out_size, void* d_ws, size_t ws_size,
                              hipStream_t stream)
{
    const float* H_l      = (const float*)d_in[0];
    const float* H_a      = (const float*)d_in[1];
    const float* W_text   = (const float*)d_in[2];
    const float* b_text   = (const float*)d_in[3];
    const float* W_audio  = (const float*)d_in[4];
    const float* b_audio  = (const float*)d_in[5];
    const float* W_out    = (const float*)d_in[6];
    const float* b_out    = (const float*)d_in[7];
    const float* g1       = (const float*)d_in[8];
    const float* beta1    = (const float*)d_in[9];
    const float* g2       = (const float*)d_in[10];
    const float* beta2    = (const float*)d_in[11];
    const float* g_out    = (const float*)d_in[12];
    const float* beta_out = (const float*)d_in[13];
    (void)in_sizes; (void)n_in; (void)out_size;

    const int B = 16, L = 1024, S = 2048, DT = 1024, DA = 768, H = 1024;

    // ---------------- workspace layout (~245.5 MiB, heavy overlay) ---------
    char* ws = (char*)d_ws;
    const size_t SZ_HLB = (size_t)B * L * DT * 2;
    const size_t SZ_HAB = (size_t)B * S * DA * 2;
    const size_t O_A    = SZ_HLB + SZ_HAB;
    const size_t SZ_A   = (size_t)B * L * H * 2;
    const size_t O_C    = O_A + SZ_A;
    const size_t SZ_C   = (size_t)B * S * H * 2;
    const size_t O_D    = O_C + SZ_C;
    const size_t SZ_D   = (size_t)B * S * H * 2;
    const size_t O_W    = O_D + SZ_D;
    const size_t need   = O_W + (size_t)(DT * H + DA * H + H * H) * 2;

    if (ws_size < need) {
        fprintf(stderr, "[kernel_launch] ws_size=%zu < needed=%zu — aborting launches\n",
                ws_size, need);
        return;
    }

    u16*   Hlb     = (u16*)(ws);
    u16*   Hab     = (u16*)(ws + SZ_HLB);
    u16*   Scores  = (u16*)(ws);                 // overlays Hlb/Hab after G2
    u16*   Abuf    = (u16*)(ws + O_A);           // text_p -> Q -> Hh
    u16*   Vbuf    = (u16*)(ws + O_C);           // audio_p = V
    u16*   Kbuf    = (u16*)(ws + O_D);           // K
    float* OutPre  = (float*)(ws + O_D);         // out_pre (after K dies)
    u16*   Wt_text  = (u16*)(ws + O_W);
    u16*   Wt_audio = Wt_text + (size_t)DT * H;
    u16*   Wt_out   = Wt_audio + (size_t)DA * H;
    u16*   Vt      = (u16*)d_out;                // dies before final LN

    const float scale = 0.03125f; // 1/sqrt(1024)

    // input casts to bf16
    cast_f32_bf16<<<(B * L * DT / 8 + 255) / 256, 256, 0, stream>>>(H_l, Hlb, (long)B * L * DT / 8);
    cast_f32_bf16<<<(B * S * DA / 8 + 255) / 256, 256, 0, stream>>>(H_a, Hab, (long)B * S * DA / 8);
    // weight transposes [K,N] -> [N,K] bf16
    tcast_f32_bf16<<<dim3(H / 32, DT / 32), dim3(32, 8), 0, stream>>>(W_text, Wt_text, DT, H);
    tcast_f32_bf16<<<dim3(H / 32, DA / 32), dim3(32, 8), 0, stream>>>(W_audio, Wt_audio, DA, H);
    tcast_f32_bf16<<<dim3(H / 32, H / 32),  dim3(32, 8), 0, stream>>>(W_out, Wt_out, H, H);

    // G1: text_p = H_l @ W_text + b_text   [16384,1024] bf16
    gemm_nt<1, true, false, true><<<dim3(H / 256, B * L / 256, 1), 512, 0, stream>>>(
        Hlb, Wt_text, Abuf, b_text, nullptr, DT, DT, DT, H, 0, 0, 0, 1.0f);
    // LN1 in-place: text_p -> Q
    ln1024<true, true><<<B * L, 256, 0, stream>>>(Abuf, g1, beta1, Abuf);

    // G2: audio_p = H_a @ W_audio + b_audio [32768,1024] bf16 (= V)
    gemm_nt<2, true, false, true><<<dim3(H / 256, B * S / 256, 1), 512, 0, stream>>>(
        Hab, Wt_audio, Vbuf, b_audio, nullptr, DA, DA, DA, H, 0, 0, 0, 1.0f);
    // LN2: audio_p -> K
    ln1024<true, true><<<B * S, 256, 0, stream>>>(Vbuf, g2, beta2, Kbuf);

    // V [S,H] -> Vt [H,S] per batch (Vt lives in d_out)
    t_bf16_batched<<<dim3(H / 32, S / 32, B), dim3(32, 8), 0, stream>>>(Vbuf, Vt, S, H);

    // G3: scores = Q @ K^T * scale          [B,1024,2048] bf16
    gemm_nt<3, false, false, true><<<dim3(S / 256, L / 256, B), 512, 0, stream>>>(
        Abuf, Kbuf, Scores, nullptr, nullptr, H, H, H, S,
        (long)L * H, (long)S * H, (long)L * S, scale);

    // softmax in-place on bf16 scores -> alpha
    softmax2048_bf16<<<B * L, 256, 0, stream>>>(Scores);

    // G5: H_hyper = alpha @ V (NT vs Vt)    [B,1024,1024] bf16 -> Abuf (Q dead)
    gemm_nt<5, false, false, true><<<dim3(H / 256, L / 256, B), 512, 0, stream>>>(
        Scores, Vt, Abuf, nullptr, nullptr, S, S, S, H,
        (long)L * S, (long)H * S, (long)L * H, 1.0f);

    // G6: out_pre = H_hyper @ W_out + b_out + H_l  [16384,1024] fp32 (K dead)
    gemm_nt<6, true, true, false><<<dim3(H / 256, B * L / 256, 1), 512, 0, stream>>>(
        Abuf, Wt_out, OutPre, b_out, H_l, H, H, H, H, 0, 0, 0, 1.0f);

    // LN3 -> d_out fp32 (Vt dead)
    ln1024<false, false><<<B * L, 256, 0, stream>>>(OutPre, g_out, beta_out, (float*)d_out);
}

// Round 8
// 552.471 us; speedup vs baseline: 1.1996x; 1.0469x over previous
//
#include <hip/hip_runtime.h>
#include <cstdio>

typedef unsigned short u16;
typedef __bf16 bf16x8 __attribute__((ext_vector_type(8)));
typedef float f32x4 __attribute__((ext_vector_type(4)));
typedef unsigned short us4 __attribute__((ext_vector_type(4)));
typedef unsigned short us8 __attribute__((ext_vector_type(8)));

__device__ __forceinline__ u16 f2bf(float f) {
    union { float f; unsigned u; } x; x.f = f;
    unsigned u = x.u + 0x7fffu + ((x.u >> 16) & 1u);   // RNE
    return (u16)(u >> 16);
}
__device__ __forceinline__ float bf2f(u16 u) {
    union { unsigned u; float f; } x; x.u = ((unsigned)u) << 16;
    return x.f;
}

// ---------------------------------------------------------------------------
// NT GEMM: C[M,N] = A[M,K] * B[N,K]^T, bf16 in, fp32 accumulate.
// 256x256 tile, BK=64, 512 threads (8 waves 2Mx4N, 128x64 per wave).
// T4-proper counted vmcnt: ALL of tile T+1's staging (8 global_load_lds per
// thread) is issued at the TOP of iteration T; s_waitcnt vmcnt(8) waits for
// the OLDEST 8 (tile T's loads, issued a full K-tile ~4k cy earlier -> ~free)
// while T+1's 8 stay in flight across every phase barrier. No mid-loop
// vmcnt(0); only the last tile drains.
// 4 quadrant phases per K-tile, each:
//   {ds_read} ; s_barrier ; lgkmcnt(0)+sched_barrier ; setprio(1) ;
//   16 MFMA (one C-quadrant x K=64) ; setprio(0) ; s_barrier.
// LDS: 2 bufs x (A 32KB + B 32KB) = 128 KiB, XOR-swizzled rows
// (phys_koff = koff ^ ((row&7)<<4)); stage pre-swizzles the GLOBAL source so
// linear global_load_lds dest + swizzled ds_read agree (both-sides rule).
// Hazard ledger:
//   RAW global->LDS: each wave passes its own vmcnt(8) (tile T's loads done)
//     then the tile-top barrier -> all waves' loads landed before any ds_read.
//   WAR: stage(T+2) writes buf d, whose ds_reads (phases 1-3 of T) are
//     drained by each wave's lgkmcnt(0) before MFMA_Q(1,0); the phase-3
//     trailing barrier therefore proves all reads done before any wave
//     reaches the top of T+1 and issues stage(T+2).
//   RAW LDS->MFMA: lgkmcnt(0) + sched_barrier(0) after each lead barrier.
// grid: (N/256, M/256, batch)
// ---------------------------------------------------------------------------

#define LDFRAG(base, row, koff) \
  (*(const bf16x8*)((const char*)(base) + (size_t)(row) * 128 + \
                    ((koff) ^ (((row) & 7) << 4))))

#define LOAD_A(QM) do { \
  _Pragma("unroll") for (int j = 0; j < 4; ++j) \
    _Pragma("unroll") for (int ks = 0; ks < 2; ++ks) \
      af[j][ks] = LDFRAG(pA, wr * 128 + (QM) * 64 + j * 16 + fr, ks * 64 + kg * 16); \
} while (0)

#define LOAD_B(QN) do { \
  _Pragma("unroll") for (int i = 0; i < 2; ++i) \
    _Pragma("unroll") for (int ks = 0; ks < 2; ++ks) \
      bfr[QN][i][ks] = LDFRAG(pB, wc * 64 + (QN) * 32 + i * 16 + fr, ks * 64 + kg * 16); \
} while (0)

#define MFMA_Q(QM, QN) do { \
  _Pragma("unroll") for (int j = 0; j < 4; ++j) \
    _Pragma("unroll") for (int i = 0; i < 2; ++i) \
      _Pragma("unroll") for (int ks = 0; ks < 2; ++ks) \
        acc[(QM) * 4 + j][(QN) * 2 + i] = __builtin_amdgcn_mfma_f32_16x16x32_bf16( \
            af[j][ks], bfr[QN][i][ks], acc[(QM) * 4 + j][(QN) * 2 + i], 0, 0, 0); \
} while (0)

#define PHASE_SYNC() do { \
  __builtin_amdgcn_s_barrier(); \
  asm volatile("s_waitcnt lgkmcnt(0)" ::: "memory"); \
  __builtin_amdgcn_sched_barrier(0); \
} while (0)

template<int TAG, bool HAS_BIAS, bool HAS_RESID, bool OUT_BF16>
__global__ __launch_bounds__(512, 2)
void gemm_nt(const u16* __restrict__ A, const u16* __restrict__ Bm,
             void* __restrict__ Cm, const float* __restrict__ bias,
             const float* __restrict__ resid,
             int K, int lda, int ldb, int ldc,
             long sA, long sB, long sC, float scale)
{
    // [buf][256 rows][64 elem] per operand; rows are 128B, XOR-swizzled.
    __shared__ __align__(16) u16 lA[2 * 256 * 64];   // 64 KiB
    __shared__ __align__(16) u16 lB[2 * 256 * 64];   // 64 KiB

    const int tid = threadIdx.x;
    const long bz = blockIdx.z;
    A  += bz * sA;
    Bm += bz * sB;
    const long cbase = bz * sC;

    // ---- block-index remap (bijective; z==1 weight GEMMs only) ----
    int bx, by;
    if (gridDim.z == 1) {
        const int gx = gridDim.x;
        const int flat = blockIdx.y * gx + blockIdx.x;
        const int q = (gx * gridDim.y) >> 3;
        const int wg = (flat & 7) * q + (flat >> 3);
        const int per = gx << 3;
        const int band = wg / per, rem = wg % per;
        bx = rem % gx;
        by = band * 8 + rem / gx;
    } else {
        bx = blockIdx.x; by = blockIdx.y;
    }
    const int m0 = by * 256;
    const int n0 = bx * 256;

    const int lane = tid & 63;
    const int w  = tid >> 6;                  // wave 0..7
    const int wr = w >> 2, wc = w & 3;        // 2x4 wave grid, 128x64 per wave
    const int fr = lane & 15;                 // A row / B col within fragment
    const int kg = lane >> 4;                 // k-group (0..3)

    // stage one half-tile (128 rows x 64 K = 16 KB) of operand op, half h,
    // K-tile kt, into buf d_. Global source pre-swizzled; LDS dest linear.
    auto stage_half = [&](int d_, int kt, int op, int h) {
        const u16* src = op ? Bm : A;
        const int  ld  = op ? ldb : lda;
        const int  bs  = op ? n0 : m0;
        u16* lds = (op ? lB : lA) + d_ * 16384 + h * 8192;
#pragma unroll
        for (int i2 = 0; i2 < 2; ++i2) {
            const int c  = i2 * 512 + tid;            // 16B chunk id, 0..1023
            const int r  = c >> 3;                    // row within half
            const int kb = ((c & 7) * 16) ^ ((r & 7) << 4);   // pre-swizzled k byte
            const u16* g = src + (size_t)(bs + h * 128 + r) * ld + kt * 64 + (kb >> 1);
            __builtin_amdgcn_global_load_lds(
                (const __attribute__((address_space(1))) void*)g,
                (__attribute__((address_space(3))) void*)(lds + (size_t)c * 8), 16, 0, 0);
        }
    };
    // full K-tile: 4 halves = 8 global_load_lds per thread (vmcnt +8)
    auto stage_tile = [&](int d_, int kt) {
        stage_half(d_, kt, 0, 0); stage_half(d_, kt, 0, 1);
        stage_half(d_, kt, 1, 0); stage_half(d_, kt, 1, 1);
    };

    f32x4 acc[8][4] = {};
    bf16x8 af[4][2];
    bf16x8 bfr[2][2][2];

    const int nt = K >> 6;
    stage_tile(0, 0);                         // pipeline fill (only cold wait)

    for (int T = 0; T < nt; ++T) {
        const int d = T & 1;
        const u16* pA = lA + d * 16384;
        const u16* pB = lB + d * 16384;

        // ---- K-tile top: issue T+1's staging, then counted wait on T's ----
        if (T + 1 < nt) {
            stage_tile(d ^ 1, T + 1);
            asm volatile("s_waitcnt vmcnt(8)" ::: "memory");   // oldest 8 = tile T
        } else {
            asm volatile("s_waitcnt vmcnt(0)" ::: "memory");   // final drain
        }
        __builtin_amdgcn_s_barrier();         // all waves' tile-T loads landed

        // ---- phase 1: quadrant (0,0)
        LOAD_A(0); LOAD_B(0);                 // 12 ds_read_b128
        PHASE_SYNC();
        __builtin_amdgcn_s_setprio(1); MFMA_Q(0, 0); __builtin_amdgcn_s_setprio(0);
        __builtin_amdgcn_s_barrier();

        // ---- phase 2: quadrant (0,1)
        LOAD_B(1);                            // 4 ds_read_b128
        PHASE_SYNC();
        __builtin_amdgcn_s_setprio(1); MFMA_Q(0, 1); __builtin_amdgcn_s_setprio(0);
        __builtin_amdgcn_s_barrier();

        // ---- phase 3: quadrant (1,0)
        LOAD_A(1);                            // 8 ds_read_b128
        PHASE_SYNC();
        __builtin_amdgcn_s_setprio(1); MFMA_Q(1, 0); __builtin_amdgcn_s_setprio(0);
        __builtin_amdgcn_s_barrier();         // proves all buf-d reads done

        // ---- phase 4: quadrant (1,1), register-only
        __builtin_amdgcn_s_setprio(1); MFMA_Q(1, 1); __builtin_amdgcn_s_setprio(0);
    }

    // epilogue: C/D layout col=lane&15, row=(lane>>4)*4+reg  [m89-verified]
    const int orow = m0 + wr * 128 + kg * 4;
    const int ocol = n0 + wc * 64 + fr;
#pragma unroll
    for (int mf = 0; mf < 8; ++mf) {
#pragma unroll
        for (int r = 0; r < 4; ++r) {
            const int m = orow + mf * 16 + r;
#pragma unroll
            for (int nf = 0; nf < 4; ++nf) {
                const int n = ocol + nf * 16;
                float v = acc[mf][nf][r] * scale;
                if (HAS_BIAS)  v += bias[n];
                if (HAS_RESID) v += resid[cbase + (long)m * ldc + n];
                if (OUT_BF16)  ((u16*)Cm)[cbase + (long)m * ldc + n] = f2bf(v);
                else           ((float*)Cm)[cbase + (long)m * ldc + n] = v;
            }
        }
    }
}

// ---------------------------------------------------------------------------
// LayerNorm over D=1024, one block (256 thr) per row.
// ---------------------------------------------------------------------------
template<bool IN_BF16, bool OUT_BF16>
__global__ __launch_bounds__(256)
void ln1024(const void* in, const float* __restrict__ g,
            const float* __restrict__ beta, void* out)
{
    const long row = blockIdx.x;
    const int tid = threadIdx.x;
    float x0, x1, x2, x3;
    if (IN_BF16) {
        const us4 v = ((const us4*)in)[row * 256 + tid];
        x0 = bf2f(v[0]); x1 = bf2f(v[1]); x2 = bf2f(v[2]); x3 = bf2f(v[3]);
    } else {
        const float4 v = ((const float4*)in)[row * 256 + tid];
        x0 = v.x; x1 = v.y; x2 = v.z; x3 = v.w;
    }
    float s  = x0 + x1 + x2 + x3;
    float s2 = x0 * x0 + x1 * x1 + x2 * x2 + x3 * x3;
#pragma unroll
    for (int off = 32; off > 0; off >>= 1) {
        s  += __shfl_xor(s, off);
        s2 += __shfl_xor(s2, off);
    }
    __shared__ float rs[4], rq[4];
    if ((tid & 63) == 0) { rs[tid >> 6] = s; rq[tid >> 6] = s2; }
    __syncthreads();
    const float S  = rs[0] + rs[1] + rs[2] + rs[3];
    const float S2 = rq[0] + rq[1] + rq[2] + rq[3];
    const float mu = S * (1.0f / 1024.0f);
    const float var = S2 * (1.0f / 1024.0f) - mu * mu;
    const float rstd = rsqrtf(var + 1e-5f);
    const float4 gg = ((const float4*)g)[tid];
    const float4 bb = ((const float4*)beta)[tid];
    const float y0 = (x0 - mu) * rstd * gg.x + bb.x;
    const float y1 = (x1 - mu) * rstd * gg.y + bb.y;
    const float y2 = (x2 - mu) * rstd * gg.z + bb.z;
    const float y3 = (x3 - mu) * rstd * gg.w + bb.w;
    if (OUT_BF16) {
        us4 o; o[0] = f2bf(y0); o[1] = f2bf(y1); o[2] = f2bf(y2); o[3] = f2bf(y3);
        ((us4*)out)[row * 256 + tid] = o;
    } else {
        float4 o; o.x = y0; o.y = y1; o.z = y2; o.w = y3;
        ((float4*)out)[row * 256 + tid] = o;
    }
}

// ---------------------------------------------------------------------------
// Softmax over width 2048, bf16 in/out, IN-PLACE. One block per row.
// ---------------------------------------------------------------------------
__global__ __launch_bounds__(256)
void softmax2048_bf16(u16* io)
{
    const long row = blockIdx.x;
    const int tid = threadIdx.x;
    const us8 v = ((const us8*)io)[row * 256 + tid];
    float x[8];
#pragma unroll
    for (int i = 0; i < 8; ++i) x[i] = bf2f(v[i]);
    float m = x[0];
#pragma unroll
    for (int i = 1; i < 8; ++i) m = fmaxf(m, x[i]);
#pragma unroll
    for (int off = 32; off > 0; off >>= 1) m = fmaxf(m, __shfl_xor(m, off));
    __shared__ float rm[4], rsum[4];
    if ((tid & 63) == 0) rm[tid >> 6] = m;
    __syncthreads();
    m = fmaxf(fmaxf(rm[0], rm[1]), fmaxf(rm[2], rm[3]));
    float e[8];
    float s = 0.f;
#pragma unroll
    for (int i = 0; i < 8; ++i) { e[i] = __expf(x[i] - m); s += e[i]; }
#pragma unroll
    for (int off = 32; off > 0; off >>= 1) s += __shfl_xor(s, off);
    if ((tid & 63) == 0) rsum[tid >> 6] = s;
    __syncthreads();
    s = rsum[0] + rsum[1] + rsum[2] + rsum[3];
    const float inv = 1.0f / s;
    us8 o;
#pragma unroll
    for (int i = 0; i < 8; ++i) o[i] = f2bf(e[i] * inv);
    ((us8*)io)[row * 256 + tid] = o;
}

// fp32 -> bf16 cast, 8 elems/thread
__global__ __launch_bounds__(256)
void cast_f32_bf16(const float* __restrict__ in, u16* __restrict__ out, long n8)
{
    const long i = (long)blockIdx.x * 256 + threadIdx.x;
    if (i >= n8) return;
    const float4 a = ((const float4*)in)[i * 2];
    const float4 b = ((const float4*)in)[i * 2 + 1];
    us8 o;
    o[0] = f2bf(a.x); o[1] = f2bf(a.y); o[2] = f2bf(a.z); o[3] = f2bf(a.w);
    o[4] = f2bf(b.x); o[5] = f2bf(b.y); o[6] = f2bf(b.z); o[7] = f2bf(b.w);
    ((us8*)out)[i] = o;
}

// transpose + cast: fp32 [R,C] -> bf16 [C,R]. block (32,8), grid (C/32, R/32)
__global__ __launch_bounds__(256)
void tcast_f32_bf16(const float* __restrict__ in, u16* __restrict__ out,
                    int R, int C)
{
    __shared__ float t[32][33];
    const int tx = threadIdx.x, ty = threadIdx.y;
    const int c0 = blockIdx.x * 32, r0 = blockIdx.y * 32;
#pragma unroll
    for (int i = 0; i < 4; ++i)
        t[ty + i * 8][tx] = in[(long)(r0 + ty + i * 8) * C + c0 + tx];
    __syncthreads();
#pragma unroll
    for (int i = 0; i < 4; ++i)
        out[(long)(c0 + ty + i * 8) * R + r0 + tx] = f2bf(t[tx][ty + i * 8]);
}

// batched bf16 transpose: [R,C] -> [C,R] per batch. grid (C/32, R/32, batch)
__global__ __launch_bounds__(256)
void t_bf16_batched(const u16* __restrict__ in, u16* __restrict__ out,
                    int R, int C)
{
    __shared__ u16 t[32][34];
    const int tx = threadIdx.x, ty = threadIdx.y;
    const int c0 = blockIdx.x * 32, r0 = blockIdx.y * 32;
    const long base = (long)blockIdx.z * R * C;
#pragma unroll
    for (int i = 0; i < 4; ++i)
        t[ty + i * 8][tx] = in[base + (long)(r0 + ty + i * 8) * C + c0 + tx];
    __syncthreads();
#pragma unroll
    for (int i = 0; i < 4; ++i)
        out[base + (long)(c0 + ty + i * 8) * R + r0 + tx] = t[tx][ty + i * 8];
}

// ---------------------------------------------------------------------------
extern "C" void kernel_launch(void* const* d_in, const int* in_sizes, int n_in,
                              void* d_out, int out_size, void* d_ws, size_t ws_size,
                              hipStream_t stream)
{
    const float* H_l      = (const float*)d_in[0];
    const float* H_a      = (const float*)d_in[1];
    const float* W_text   = (const float*)d_in[2];
    const float* b_text   = (const float*)d_in[3];
    const float* W_audio  = (const float*)d_in[4];
    const float* b_audio  = (const float*)d_in[5];
    const float* W_out    = (const float*)d_in[6];
    const float* b_out    = (const float*)d_in[7];
    const float* g1       = (const float*)d_in[8];
    const float* beta1    = (const float*)d_in[9];
    const float* g2       = (const float*)d_in[10];
    const float* beta2    = (const float*)d_in[11];
    const float* g_out    = (const float*)d_in[12];
    const float* beta_out = (const float*)d_in[13];
    (void)in_sizes; (void)n_in; (void)out_size;

    const int B = 16, L = 1024, S = 2048, DT = 1024, DA = 768, H = 1024;

    // ---------------- workspace layout (~245.5 MiB, heavy overlay) ---------
    char* ws = (char*)d_ws;
    const size_t SZ_HLB = (size_t)B * L * DT * 2;
    const size_t SZ_HAB = (size_t)B * S * DA * 2;
    const size_t O_A    = SZ_HLB + SZ_HAB;
    const size_t SZ_A   = (size_t)B * L * H * 2;
    const size_t O_C    = O_A + SZ_A;
    const size_t SZ_C   = (size_t)B * S * H * 2;
    const size_t O_D    = O_C + SZ_C;
    const size_t SZ_D   = (size_t)B * S * H * 2;
    const size_t O_W    = O_D + SZ_D;
    const size_t need   = O_W + (size_t)(DT * H + DA * H + H * H) * 2;

    if (ws_size < need) {
        fprintf(stderr, "[kernel_launch] ws_size=%zu < needed=%zu — aborting launches\n",
                ws_size, need);
        return;
    }

    u16*   Hlb     = (u16*)(ws);
    u16*   Hab     = (u16*)(ws + SZ_HLB);
    u16*   Scores  = (u16*)(ws);                 // overlays Hlb/Hab after G2
    u16*   Abuf    = (u16*)(ws + O_A);           // text_p -> Q -> Hh
    u16*   Vbuf    = (u16*)(ws + O_C);           // audio_p = V
    u16*   Kbuf    = (u16*)(ws + O_D);           // K
    float* OutPre  = (float*)(ws + O_D);         // out_pre (after K dies)
    u16*   Wt_text  = (u16*)(ws + O_W);
    u16*   Wt_audio = Wt_text + (size_t)DT * H;
    u16*   Wt_out   = Wt_audio + (size_t)DA * H;
    u16*   Vt      = (u16*)d_out;                // dies before final LN

    const float scale = 0.03125f; // 1/sqrt(1024)

    // input casts to bf16
    cast_f32_bf16<<<(B * L * DT / 8 + 255) / 256, 256, 0, stream>>>(H_l, Hlb, (long)B * L * DT / 8);
    cast_f32_bf16<<<(B * S * DA / 8 + 255) / 256, 256, 0, stream>>>(H_a, Hab, (long)B * S * DA / 8);
    // weight transposes [K,N] -> [N,K] bf16
    tcast_f32_bf16<<<dim3(H / 32, DT / 32), dim3(32, 8), 0, stream>>>(W_text, Wt_text, DT, H);
    tcast_f32_bf16<<<dim3(H / 32, DA / 32), dim3(32, 8), 0, stream>>>(W_audio, Wt_audio, DA, H);
    tcast_f32_bf16<<<dim3(H / 32, H / 32),  dim3(32, 8), 0, stream>>>(W_out, Wt_out, H, H);

    // G1: text_p = H_l @ W_text + b_text   [16384,1024] bf16
    gemm_nt<1, true, false, true><<<dim3(H / 256, B * L / 256, 1), 512, 0, stream>>>(
        Hlb, Wt_text, Abuf, b_text, nullptr, DT, DT, DT, H, 0, 0, 0, 1.0f);
    // LN1 in-place: text_p -> Q
    ln1024<true, true><<<B * L, 256, 0, stream>>>(Abuf, g1, beta1, Abuf);

    // G2: audio_p = H_a @ W_audio + b_audio [32768,1024] bf16 (= V)
    gemm_nt<2, true, false, true><<<dim3(H / 256, B * S / 256, 1), 512, 0, stream>>>(
        Hab, Wt_audio, Vbuf, b_audio, nullptr, DA, DA, DA, H, 0, 0, 0, 1.0f);
    // LN2: audio_p -> K
    ln1024<true, true><<<B * S, 256, 0, stream>>>(Vbuf, g2, beta2, Kbuf);

    // V [S,H] -> Vt [H,S] per batch (Vt lives in d_out)
    t_bf16_batched<<<dim3(H / 32, S / 32, B), dim3(32, 8), 0, stream>>>(Vbuf, Vt, S, H);

    // G3: scores = Q @ K^T * scale          [B,1024,2048] bf16
    gemm_nt<3, false, false, true><<<dim3(S / 256, L / 256, B), 512, 0, stream>>>(
        Abuf, Kbuf, Scores, nullptr, nullptr, H, H, H, S,
        (long)L * H, (long)S * H, (long)L * S, scale);

    // softmax in-place on bf16 scores -> alpha
    softmax2048_bf16<<<B * L, 256, 0, stream>>>(Scores);

    // G5: H_hyper = alpha @ V (NT vs Vt)    [B,1024,1024] bf16 -> Abuf (Q dead)
    gemm_nt<5, false, false, true><<<dim3(H / 256, L / 256, B), 512, 0, stream>>>(
        Scores, Vt, Abuf, nullptr, nullptr, S, S, S, H,
        (long)L * S, (long)H * S, (long)L * H, 1.0f);

    // G6: out_pre = H_hyper @ W_out + b_out + H_l  [16384,1024] fp32 (K dead)
    gemm_nt<6, true, true, false><<<dim3(H / 256, B * L / 256, 1), 512, 0, stream>>>(
        Abuf, Wt_out, OutPre, b_out, H_l, H, H, H, H, 0, 0, 0, 1.0f);

    // LN3 -> d_out fp32 (Vt dead)
    ln1024<false, false><<<B * L, 256, 0, stream>>>(OutPre, g_out, beta_out, (float*)d_out);
}

// Round 9
// 535.609 us; speedup vs baseline: 1.2374x; 1.0315x over previous
//
#include <hip/hip_runtime.h>
#include <cstdio>

typedef unsigned short u16;
typedef __bf16 bf16x8 __attribute__((ext_vector_type(8)));
typedef float f32x4 __attribute__((ext_vector_type(4)));
typedef unsigned short us4 __attribute__((ext_vector_type(4)));
typedef unsigned short us8 __attribute__((ext_vector_type(8)));

__device__ __forceinline__ u16 f2bf(float f) {
    union { float f; unsigned u; } x; x.f = f;
    unsigned u = x.u + 0x7fffu + ((x.u >> 16) & 1u);   // RNE
    return (u16)(u >> 16);
}
__device__ __forceinline__ float bf2f(u16 u) {
    union { unsigned u; float f; } x; x.u = ((unsigned)u) << 16;
    return x.f;
}

// ---------------------------------------------------------------------------
// NT GEMM: C[M,N] = A[M,K] * B[N,K]^T, bf16 in, fp32 accumulate.
// 256x256 tile, BK=64, 512 threads (8 waves 2Mx4N, 128x64 per wave).
// Counted vmcnt: all of tile T+1's staging (8 global_load_lds/thread) issued
// at the TOP of iteration T; s_waitcnt vmcnt(8) waits only for tile T's loads
// (issued a full K-tile earlier) while T+1's stay in flight. No mid-loop
// vmcnt(0).
// 4 quadrant phases per K-tile: {ds_read ; s_barrier ; setprio(1) ; 16 MFMA ;
// setprio(0) ; s_barrier}. NO inline lgkmcnt/sched_barrier: ds_reads are
// plain C++ loads, so the compiler inserts fine-grained per-use lgkmcnt and
// may interleave reads/VALU with MFMA (m141: blanket pinning costs ~1.7x).
// LDS: 2 bufs x (A 32KB + B 32KB) = 128 KiB, XOR-swizzled rows
// (phys_koff = koff ^ ((row&7)<<4)); stage pre-swizzles the GLOBAL source so
// linear global_load_lds dest + swizzled ds_read agree (both-sides rule).
// Hazard ledger:
//   RAW global->LDS: each wave passes vmcnt(8) (tile T's loads done) then the
//     tile-top barrier -> all waves' loads landed before any ds_read of T.
//   WAR: stage(T+2) writes buf d; every ds_read of buf d is consumed by an
//     MFMA in its own phase (compiler lgkmcnt before use), so reads complete
//     before each wave passes that phase's trailing barrier; stage(T+2) is
//     issued only after the top-of-T+1 barrier which follows phase 3's
//     trailing barrier.
//   RAW LDS->MFMA: compiler-inserted lgkmcnt (plain C++ loads).
// EMIT_VT (G2 only): epilogue additionally writes V^T[b][n][s] (batch 2048
// rows) from registers -> kills the separate transpose kernel.
// grid: (N/256, M/256, batch); all grids divisible by 8 for the XCD remap.
// ---------------------------------------------------------------------------

#define LDFRAG(base, row, koff) \
  (*(const bf16x8*)((const char*)(base) + (size_t)(row) * 128 + \
                    ((koff) ^ (((row) & 7) << 4))))

#define LOAD_A(QM) do { \
  _Pragma("unroll") for (int j = 0; j < 4; ++j) \
    _Pragma("unroll") for (int ks = 0; ks < 2; ++ks) \
      af[j][ks] = LDFRAG(pA, wr * 128 + (QM) * 64 + j * 16 + fr, ks * 64 + kg * 16); \
} while (0)

#define LOAD_B(QN) do { \
  _Pragma("unroll") for (int i = 0; i < 2; ++i) \
    _Pragma("unroll") for (int ks = 0; ks < 2; ++ks) \
      bfr[QN][i][ks] = LDFRAG(pB, wc * 64 + (QN) * 32 + i * 16 + fr, ks * 64 + kg * 16); \
} while (0)

#define MFMA_Q(QM, QN) do { \
  _Pragma("unroll") for (int j = 0; j < 4; ++j) \
    _Pragma("unroll") for (int i = 0; i < 2; ++i) \
      _Pragma("unroll") for (int ks = 0; ks < 2; ++ks) \
        acc[(QM) * 4 + j][(QN) * 2 + i] = __builtin_amdgcn_mfma_f32_16x16x32_bf16( \
            af[j][ks], bfr[QN][i][ks], acc[(QM) * 4 + j][(QN) * 2 + i], 0, 0, 0); \
} while (0)

#define BARRIER() do { \
  __builtin_amdgcn_s_barrier(); \
  asm volatile("" ::: "memory"); \
} while (0)

template<int TAG, bool HAS_BIAS, bool HAS_RESID, bool OUT_BF16, bool EMIT_VT>
__global__ __launch_bounds__(512, 2)
void gemm_nt(const u16* __restrict__ A, const u16* __restrict__ Bm,
             void* __restrict__ Cm, const float* __restrict__ bias,
             const float* __restrict__ resid, u16* __restrict__ vt,
             int K, int lda, int ldb, int ldc,
             long sA, long sB, long sC, float scale)
{
    // [buf][256 rows][64 elem] per operand; rows are 128B, XOR-swizzled.
    __shared__ __align__(16) u16 lA[2 * 256 * 64];   // 64 KiB
    __shared__ __align__(16) u16 lB[2 * 256 * 64];   // 64 KiB

    const int tid = threadIdx.x;

    // ---- bijective XCD chunking over the flattened 3D grid (nwg%8==0) ----
    const int gx = gridDim.x, gy = gridDim.y;
    {
    }
    int flat = ((int)blockIdx.z * gy + blockIdx.y) * gx + blockIdx.x;
    const int nwg = gx * gy * (int)gridDim.z;
    const int q = nwg >> 3;
    flat = (flat & 7) * q + (flat >> 3);
    const int bx = flat % gx;
    const int t2 = flat / gx;
    const int by = t2 % gy;
    const long bz = t2 / gy;

    A  += bz * sA;
    Bm += bz * sB;
    const long cbase = bz * sC;
    const int m0 = by * 256;
    const int n0 = bx * 256;

    const int lane = tid & 63;
    const int w  = tid >> 6;                  // wave 0..7
    const int wr = w >> 2, wc = w & 3;        // 2x4 wave grid, 128x64 per wave
    const int fr = lane & 15;                 // A row / B col within fragment
    const int kg = lane >> 4;                 // k-group (0..3)

    // stage one half-tile (128 rows x 64 K = 16 KB) of operand op, half h,
    // K-tile kt, into buf d_. Global source pre-swizzled; LDS dest linear.
    auto stage_half = [&](int d_, int kt, int op, int h) {
        const u16* src = op ? Bm : A;
        const int  ld  = op ? ldb : lda;
        const int  bs  = op ? n0 : m0;
        u16* lds = (op ? lB : lA) + d_ * 16384 + h * 8192;
#pragma unroll
        for (int i2 = 0; i2 < 2; ++i2) {
            const int c  = i2 * 512 + tid;            // 16B chunk id, 0..1023
            const int r  = c >> 3;                    // row within half
            const int kb = ((c & 7) * 16) ^ ((r & 7) << 4);   // pre-swizzled k byte
            const u16* g = src + (size_t)(bs + h * 128 + r) * ld + kt * 64 + (kb >> 1);
            __builtin_amdgcn_global_load_lds(
                (const __attribute__((address_space(1))) void*)g,
                (__attribute__((address_space(3))) void*)(lds + (size_t)c * 8), 16, 0, 0);
        }
    };
    // full K-tile: 4 halves = 8 global_load_lds per thread (vmcnt +8)
    auto stage_tile = [&](int d_, int kt) {
        stage_half(d_, kt, 0, 0); stage_half(d_, kt, 0, 1);
        stage_half(d_, kt, 1, 0); stage_half(d_, kt, 1, 1);
    };

    f32x4 acc[8][4] = {};
    bf16x8 af[4][2];
    bf16x8 bfr[2][2][2];

    const int nt = K >> 6;
    stage_tile(0, 0);                         // pipeline fill (only cold wait)

    for (int T = 0; T < nt; ++T) {
        const int d = T & 1;
        const u16* pA = lA + d * 16384;
        const u16* pB = lB + d * 16384;

        // ---- K-tile top: issue T+1's staging, counted wait on T's ----
        if (T + 1 < nt) {
            stage_tile(d ^ 1, T + 1);
            asm volatile("s_waitcnt vmcnt(8)" ::: "memory");   // oldest 8 = tile T
        } else {
            asm volatile("s_waitcnt vmcnt(0)" ::: "memory");   // final drain
        }
        BARRIER();                            // all waves' tile-T loads landed

        // ---- phase 1: quadrant (0,0)
        LOAD_A(0); LOAD_B(0);                 // 12 ds_read_b128
        BARRIER();
        __builtin_amdgcn_s_setprio(1); MFMA_Q(0, 0); __builtin_amdgcn_s_setprio(0);
        BARRIER();

        // ---- phase 2: quadrant (0,1)
        LOAD_B(1);                            // 4 ds_read_b128
        BARRIER();
        __builtin_amdgcn_s_setprio(1); MFMA_Q(0, 1); __builtin_amdgcn_s_setprio(0);
        BARRIER();

        // ---- phase 3: quadrant (1,0)
        LOAD_A(1);                            // 8 ds_read_b128
        BARRIER();
        __builtin_amdgcn_s_setprio(1); MFMA_Q(1, 0); __builtin_amdgcn_s_setprio(0);
        BARRIER();                            // proves all buf-d reads done

        // ---- phase 4: quadrant (1,1), register-only
        __builtin_amdgcn_s_setprio(1); MFMA_Q(1, 1); __builtin_amdgcn_s_setprio(0);
    }

    // epilogue: C/D layout col=lane&15, row=(lane>>4)*4+reg  [m89-verified]
    const int orow = m0 + wr * 128 + kg * 4;
    const int ocol = n0 + wc * 64 + fr;
#pragma unroll
    for (int mf = 0; mf < 8; ++mf) {
        const int mbase = orow + mf * 16;     // 4 consecutive rows mbase..+3
#pragma unroll
        for (int nf = 0; nf < 4; ++nf) {
            const int n = ocol + nf * 16;
            float v4[4];
#pragma unroll
            for (int r = 0; r < 4; ++r) {
                const int m = mbase + r;
                float v = acc[mf][nf][r] * scale;
                if (HAS_BIAS)  v += bias[n];
                if (HAS_RESID) v += resid[cbase + (long)m * ldc + n];
                v4[r] = v;
                if (OUT_BF16)  ((u16*)Cm)[cbase + (long)m * ldc + n] = f2bf(v);
                else           ((float*)Cm)[cbase + (long)m * ldc + n] = v;
            }
            if (EMIT_VT) {
                // rows m = b*2048 + s; write Vt[b][n][s..s+3] (batch S=2048)
                const long b  = mbase >> 11;
                const int  s  = mbase & 2047;
                us4 o;
#pragma unroll
                for (int r = 0; r < 4; ++r) o[r] = f2bf(v4[r]);
                *(us4*)(vt + (b * 1024 + n) * 2048 + s) = o;
            }
        }
    }
}

// ---------------------------------------------------------------------------
// LayerNorm over D=1024, one block (256 thr) per row.
// ---------------------------------------------------------------------------
template<bool IN_BF16, bool OUT_BF16>
__global__ __launch_bounds__(256)
void ln1024(const void* in, const float* __restrict__ g,
            const float* __restrict__ beta, void* out)
{
    const long row = blockIdx.x;
    const int tid = threadIdx.x;
    float x0, x1, x2, x3;
    if (IN_BF16) {
        const us4 v = ((const us4*)in)[row * 256 + tid];
        x0 = bf2f(v[0]); x1 = bf2f(v[1]); x2 = bf2f(v[2]); x3 = bf2f(v[3]);
    } else {
        const float4 v = ((const float4*)in)[row * 256 + tid];
        x0 = v.x; x1 = v.y; x2 = v.z; x3 = v.w;
    }
    float s  = x0 + x1 + x2 + x3;
    float s2 = x0 * x0 + x1 * x1 + x2 * x2 + x3 * x3;
#pragma unroll
    for (int off = 32; off > 0; off >>= 1) {
        s  += __shfl_xor(s, off);
        s2 += __shfl_xor(s2, off);
    }
    __shared__ float rs[4], rq[4];
    if ((tid & 63) == 0) { rs[tid >> 6] = s; rq[tid >> 6] = s2; }
    __syncthreads();
    const float S  = rs[0] + rs[1] + rs[2] + rs[3];
    const float S2 = rq[0] + rq[1] + rq[2] + rq[3];
    const float mu = S * (1.0f / 1024.0f);
    const float var = S2 * (1.0f / 1024.0f) - mu * mu;
    const float rstd = rsqrtf(var + 1e-5f);
    const float4 gg = ((const float4*)g)[tid];
    const float4 bb = ((const float4*)beta)[tid];
    const float y0 = (x0 - mu) * rstd * gg.x + bb.x;
    const float y1 = (x1 - mu) * rstd * gg.y + bb.y;
    const float y2 = (x2 - mu) * rstd * gg.z + bb.z;
    const float y3 = (x3 - mu) * rstd * gg.w + bb.w;
    if (OUT_BF16) {
        us4 o; o[0] = f2bf(y0); o[1] = f2bf(y1); o[2] = f2bf(y2); o[3] = f2bf(y3);
        ((us4*)out)[row * 256 + tid] = o;
    } else {
        float4 o; o.x = y0; o.y = y1; o.z = y2; o.w = y3;
        ((float4*)out)[row * 256 + tid] = o;
    }
}

// ---------------------------------------------------------------------------
// Softmax over width 2048, bf16 in/out, IN-PLACE. One block per row.
// ---------------------------------------------------------------------------
__global__ __launch_bounds__(256)
void softmax2048_bf16(u16* io)
{
    const long row = blockIdx.x;
    const int tid = threadIdx.x;
    const us8 v = ((const us8*)io)[row * 256 + tid];
    float x[8];
#pragma unroll
    for (int i = 0; i < 8; ++i) x[i] = bf2f(v[i]);
    float m = x[0];
#pragma unroll
    for (int i = 1; i < 8; ++i) m = fmaxf(m, x[i]);
#pragma unroll
    for (int off = 32; off > 0; off >>= 1) m = fmaxf(m, __shfl_xor(m, off));
    __shared__ float rm[4], rsum[4];
    if ((tid & 63) == 0) rm[tid >> 6] = m;
    __syncthreads();
    m = fmaxf(fmaxf(rm[0], rm[1]), fmaxf(rm[2], rm[3]));
    float e[8];
    float s = 0.f;
#pragma unroll
    for (int i = 0; i < 8; ++i) { e[i] = __expf(x[i] - m); s += e[i]; }
#pragma unroll
    for (int off = 32; off > 0; off >>= 1) s += __shfl_xor(s, off);
    if ((tid & 63) == 0) rsum[tid >> 6] = s;
    __syncthreads();
    s = rsum[0] + rsum[1] + rsum[2] + rsum[3];
    const float inv = 1.0f / s;
    us8 o;
#pragma unroll
    for (int i = 0; i < 8; ++i) o[i] = f2bf(e[i] * inv);
    ((us8*)io)[row * 256 + tid] = o;
}

// fp32 -> bf16 cast, 8 elems/thread
__global__ __launch_bounds__(256)
void cast_f32_bf16(const float* __restrict__ in, u16* __restrict__ out, long n8)
{
    const long i = (long)blockIdx.x * 256 + threadIdx.x;
    if (i >= n8) return;
    const float4 a = ((const float4*)in)[i * 2];
    const float4 b = ((const float4*)in)[i * 2 + 1];
    us8 o;
    o[0] = f2bf(a.x); o[1] = f2bf(a.y); o[2] = f2bf(a.z); o[3] = f2bf(a.w);
    o[4] = f2bf(b.x); o[5] = f2bf(b.y); o[6] = f2bf(b.z); o[7] = f2bf(b.w);
    ((us8*)out)[i] = o;
}

// transpose + cast: fp32 [R,C] -> bf16 [C,R]. block (32,8), grid (C/32, R/32)
__global__ __launch_bounds__(256)
void tcast_f32_bf16(const float* __restrict__ in, u16* __restrict__ out,
                    int R, int C)
{
    __shared__ float t[32][33];
    const int tx = threadIdx.x, ty = threadIdx.y;
    const int c0 = blockIdx.x * 32, r0 = blockIdx.y * 32;
#pragma unroll
    for (int i = 0; i < 4; ++i)
        t[ty + i * 8][tx] = in[(long)(r0 + ty + i * 8) * C + c0 + tx];
    __syncthreads();
#pragma unroll
    for (int i = 0; i < 4; ++i)
        out[(long)(c0 + ty + i * 8) * R + r0 + tx] = f2bf(t[tx][ty + i * 8]);
}

// ---------------------------------------------------------------------------
extern "C" void kernel_launch(void* const* d_in, const int* in_sizes, int n_in,
                              void* d_out, int out_size, void* d_ws, size_t ws_size,
                              hipStream_t stream)
{
    const float* H_l      = (const float*)d_in[0];
    const float* H_a      = (const float*)d_in[1];
    const float* W_text   = (const float*)d_in[2];
    const float* b_text   = (const float*)d_in[3];
    const float* W_audio  = (const float*)d_in[4];
    const float* b_audio  = (const float*)d_in[5];
    const float* W_out    = (const float*)d_in[6];
    const float* b_out    = (const float*)d_in[7];
    const float* g1       = (const float*)d_in[8];
    const float* beta1    = (const float*)d_in[9];
    const float* g2       = (const float*)d_in[10];
    const float* beta2    = (const float*)d_in[11];
    const float* g_out    = (const float*)d_in[12];
    const float* beta_out = (const float*)d_in[13];
    (void)in_sizes; (void)n_in; (void)out_size;

    const int B = 16, L = 1024, S = 2048, DT = 1024, DA = 768, H = 1024;

    // ---------------- workspace layout (~245.5 MiB, heavy overlay) ---------
    char* ws = (char*)d_ws;
    const size_t SZ_HLB = (size_t)B * L * DT * 2;
    const size_t SZ_HAB = (size_t)B * S * DA * 2;
    const size_t O_A    = SZ_HLB + SZ_HAB;
    const size_t SZ_A   = (size_t)B * L * H * 2;
    const size_t O_C    = O_A + SZ_A;
    const size_t SZ_C   = (size_t)B * S * H * 2;
    const size_t O_D    = O_C + SZ_C;
    const size_t SZ_D   = (size_t)B * S * H * 2;
    const size_t O_W    = O_D + SZ_D;
    const size_t need   = O_W + (size_t)(DT * H + DA * H + H * H) * 2;

    if (ws_size < need) {
        fprintf(stderr, "[kernel_launch] ws_size=%zu < needed=%zu — aborting launches\n",
                ws_size, need);
        return;
    }

    u16*   Hlb     = (u16*)(ws);
    u16*   Hab     = (u16*)(ws + SZ_HLB);
    u16*   Scores  = (u16*)(ws);                 // overlays Hlb/Hab after G2
    u16*   Abuf    = (u16*)(ws + O_A);           // text_p -> Q -> Hh
    u16*   Vbuf    = (u16*)(ws + O_C);           // audio_p (LN2 input)
    u16*   Kbuf    = (u16*)(ws + O_D);           // K
    u16*   OutPre  = (u16*)(ws + O_D);           // out_pre bf16 (after K dies)
    u16*   Wt_text  = (u16*)(ws + O_W);
    u16*   Wt_audio = Wt_text + (size_t)DT * H;
    u16*   Wt_out   = Wt_audio + (size_t)DA * H;
    u16*   Vt      = (u16*)d_out;                // dies before final LN

    const float scale = 0.03125f; // 1/sqrt(1024)

    // input casts to bf16
    cast_f32_bf16<<<(B * L * DT / 8 + 255) / 256, 256, 0, stream>>>(H_l, Hlb, (long)B * L * DT / 8);
    cast_f32_bf16<<<(B * S * DA / 8 + 255) / 256, 256, 0, stream>>>(H_a, Hab, (long)B * S * DA / 8);
    // weight transposes [K,N] -> [N,K] bf16
    tcast_f32_bf16<<<dim3(H / 32, DT / 32), dim3(32, 8), 0, stream>>>(W_text, Wt_text, DT, H);
    tcast_f32_bf16<<<dim3(H / 32, DA / 32), dim3(32, 8), 0, stream>>>(W_audio, Wt_audio, DA, H);
    tcast_f32_bf16<<<dim3(H / 32, H / 32),  dim3(32, 8), 0, stream>>>(W_out, Wt_out, H, H);

    // G1: text_p = H_l @ W_text + b_text   [16384,1024] bf16
    gemm_nt<1, true, false, true, false><<<dim3(H / 256, B * L / 256, 1), 512, 0, stream>>>(
        Hlb, Wt_text, Abuf, b_text, nullptr, nullptr, DT, DT, DT, H, 0, 0, 0, 1.0f);
    // LN1 in-place: text_p -> Q
    ln1024<true, true><<<B * L, 256, 0, stream>>>(Abuf, g1, beta1, Abuf);

    // G2: audio_p = H_a @ W_audio + b_audio [32768,1024] bf16 (= V),
    //     epilogue also writes V^T into Vt (d_out) -> no transpose kernel
    gemm_nt<2, true, false, true, true><<<dim3(H / 256, B * S / 256, 1), 512, 0, stream>>>(
        Hab, Wt_audio, Vbuf, b_audio, nullptr, Vt, DA, DA, DA, H, 0, 0, 0, 1.0f);
    // LN2: audio_p -> K
    ln1024<true, true><<<B * S, 256, 0, stream>>>(Vbuf, g2, beta2, Kbuf);

    // G3: scores = Q @ K^T * scale          [B,1024,2048] bf16
    gemm_nt<3, false, false, true, false><<<dim3(S / 256, L / 256, B), 512, 0, stream>>>(
        Abuf, Kbuf, Scores, nullptr, nullptr, nullptr, H, H, H, S,
        (long)L * H, (long)S * H, (long)L * S, scale);

    // softmax in-place on bf16 scores -> alpha
    softmax2048_bf16<<<B * L, 256, 0, stream>>>(Scores);

    // G5: H_hyper = alpha @ V (NT vs Vt)    [B,1024,1024] bf16 -> Abuf (Q dead)
    gemm_nt<5, false, false, true, false><<<dim3(H / 256, L / 256, B), 512, 0, stream>>>(
        Scores, Vt, Abuf, nullptr, nullptr, nullptr, S, S, S, H,
        (long)L * S, (long)H * S, (long)L * H, 1.0f);

    // G6: out_pre = H_hyper @ W_out + b_out + H_l  [16384,1024] bf16 (K dead)
    gemm_nt<6, true, true, true, false><<<dim3(H / 256, B * L / 256, 1), 512, 0, stream>>>(
        Abuf, Wt_out, OutPre, b_out, H_l, nullptr, H, H, H, H, 0, 0, 0, 1.0f);

    // LN3 (bf16 in) -> d_out fp32 (Vt dead)
    ln1024<true, false><<<B * L, 256, 0, stream>>>(OutPre, g_out, beta_out, (float*)d_out);
}